// Round 1
// baseline (813.217 us; speedup 1.0000x reference)
//
#include <hip/hip_runtime.h>
#include <hip/hip_bf16.h>
#include <stdint.h>
#include <stddef.h>

#define HW 262144          // 512*512
#define EPSF 1e-5f

typedef __hip_bfloat16 bf16;

__device__ __forceinline__ float b2f(bf16 v){ return __bfloat162float(v); }
__device__ __forceinline__ bf16  f2b(float v){ return __float2bfloat16(v); }
__device__ __forceinline__ float lrelu(float v){ return v > 0.0f ? v : 0.01f * v; }

// ---------------------------------------------------------------------------
// K0a: quantize x to level k = rint(x*255/16), materialize reflect-padded u8
// plane [6][522 rows][pitch 528]
// ---------------------------------------------------------------------------
__global__ __launch_bounds__(256) void k_quant_pad(const float* __restrict__ x,
                                                   uint8_t* __restrict__ qpad){
  int idx = blockIdx.x * 256 + threadIdx.x;
  if (idx >= 6 * 522 * 522) return;
  int pw = idx % 522; int t = idx / 522; int ph = t % 522; int img = t / 522;
  int h = ph - 5; h = h < 0 ? -h : h; if (h > 511) h = 1022 - h;
  int w = pw - 5; w = w < 0 ? -w : w; if (w > 511) w = 1022 - w;
  float v = x[img * HW + h * 512 + w];
  int k = (int)rintf((v * 255.0f) / 16.0f);   // round-half-even, matches jnp.round
  qpad[img * (522 * 528) + ph * 528 + pw] = (uint8_t)k;
}

// ---------------------------------------------------------------------------
// K0b: 11x11 mode filter. Thread = 8 consecutive output pixels in one row,
// sliding 17-bin histogram packed 8-bit into 5 u32 registers.
// Block 256 = 4 rows x 64 threads. Grid = 6 imgs * 128.
// ---------------------------------------------------------------------------
__global__ __launch_bounds__(256) void k_mode(const uint8_t* __restrict__ qpad,
                                              uint8_t* __restrict__ xm){
  int tid = threadIdx.x;
  int img = blockIdx.x >> 7;
  int h   = ((blockIdx.x & 127) << 2) + (tid >> 6);
  int w0  = (tid & 63) << 3;
  const uint8_t* base = qpad + img * (522 * 528);
  uint32_t c0 = 0, c1 = 0, c2 = 0, c3 = 0, c4 = 0;
#define HINC(qv) { uint32_t inc = 1u << (((qv) & 3) << 3); int r = (qv) >> 2; \
    if (r == 0) c0 += inc; else if (r == 1) c1 += inc; else if (r == 2) c2 += inc; \
    else if (r == 3) c3 += inc; else c4 += inc; }
#define HDEC(qv) { uint32_t inc = 1u << (((qv) & 3) << 3); int r = (qv) >> 2; \
    if (r == 0) c0 -= inc; else if (r == 1) c1 -= inc; else if (r == 2) c2 -= inc; \
    else if (r == 3) c3 -= inc; else c4 -= inc; }
  for (int dy = 0; dy < 11; ++dy){
    const uint8_t* row = base + (h + dy) * 528 + w0;
    #pragma unroll
    for (int dx = 0; dx < 11; ++dx){ int q = row[dx]; HINC(q); }
  }
  uint64_t packed = 0;
  for (int s = 0; ; ++s){
    int best = 0, bc = -1;
#define CHK(l, reg, sh) { int cnt = (int)(((reg) >> (sh)) & 0xffu); if (cnt > bc){ bc = cnt; best = (l); } }
    CHK(0,c0,0)  CHK(1,c0,8)  CHK(2,c0,16)  CHK(3,c0,24)
    CHK(4,c1,0)  CHK(5,c1,8)  CHK(6,c1,16)  CHK(7,c1,24)
    CHK(8,c2,0)  CHK(9,c2,8)  CHK(10,c2,16) CHK(11,c2,24)
    CHK(12,c3,0) CHK(13,c3,8) CHK(14,c3,16) CHK(15,c3,24)
    CHK(16,c4,0)
#undef CHK
    packed |= ((uint64_t)(uint8_t)best) << (8 * s);
    if (s == 7) break;
    for (int dy = 0; dy < 11; ++dy){
      const uint8_t* row = base + (h + dy) * 528 + w0;
      int qo = row[s];      HDEC(qo);
      int qn = row[s + 11]; HINC(qn);
    }
  }
#undef HINC
#undef HDEC
  *(uint64_t*)(xm + img * HW + h * 512 + w0) = packed;
}

// ---------------------------------------------------------------------------
// block reduction of per-thread su[16]/sq[16] -> partials[block][32]
// ---------------------------------------------------------------------------
__device__ __forceinline__ void reduce16(float* su, float* sq, float* __restrict__ partials){
  __shared__ float lsum[32];
  int tid = threadIdx.x;
  if (tid < 32) lsum[tid] = 0.0f;
  __syncthreads();
  #pragma unroll
  for (int o = 0; o < 16; ++o){
    float s = su[o], q = sq[o];
    #pragma unroll
    for (int off = 32; off >= 1; off >>= 1){
      s += __shfl_xor(s, off);
      q += __shfl_xor(q, off);
    }
    if ((tid & 63) == 0){ atomicAdd(&lsum[o], s); atomicAdd(&lsum[16 + o], q); }
  }
  __syncthreads();
  if (tid < 32) partials[blockIdx.x * 32 + tid] = lsum[tid];
}

// ---------------------------------------------------------------------------
// K1: stats of p1 = conv1x1(xm) (no write). grid 2048 x 256 (one pixel/thread)
// ---------------------------------------------------------------------------
__global__ __launch_bounds__(256) void k_stats1(const uint8_t* __restrict__ xm,
                                                const float* __restrict__ w1,
                                                const float* __restrict__ b1,
                                                float* __restrict__ partials){
  int pix = blockIdx.x * 256 + threadIdx.x;
  int b = pix >> 18, hw = pix & (HW - 1);
  float x0 = xm[(b * 3 + 0) * HW + hw] * 0.0625f;
  float x1 = xm[(b * 3 + 1) * HW + hw] * 0.0625f;
  float x2 = xm[(b * 3 + 2) * HW + hw] * 0.0625f;
  float su[16], sq[16];
  #pragma unroll
  for (int o = 0; o < 16; ++o){
    float v = b1[o] + w1[o*3]*x0 + w1[o*3+1]*x1 + w1[o*3+2]*x2;
    su[o] = v; sq[o] = v * v;
  }
  reduce16(su, sq, partials);
}

// ---------------------------------------------------------------------------
// K2: recompute p1, apply bn1+lrelu, p2 = conv1x1, stats of p2 (no write)
// ---------------------------------------------------------------------------
__global__ __launch_bounds__(256) void k_stats2(const uint8_t* __restrict__ xm,
                                                const float* __restrict__ w1,
                                                const float* __restrict__ b1,
                                                const float* __restrict__ w2,
                                                const float* __restrict__ b2,
                                                const float* __restrict__ params,
                                                float* __restrict__ partials){
  int pix = blockIdx.x * 256 + threadIdx.x;
  int b = pix >> 18, hw = pix & (HW - 1);
  float x0 = xm[(b * 3 + 0) * HW + hw] * 0.0625f;
  float x1 = xm[(b * 3 + 1) * HW + hw] * 0.0625f;
  float x2 = xm[(b * 3 + 2) * HW + hw] * 0.0625f;
  float tv[16];
  #pragma unroll
  for (int o = 0; o < 16; ++o){
    float v = b1[o] + w1[o*3]*x0 + w1[o*3+1]*x1 + w1[o*3+2]*x2;
    tv[o] = lrelu(v * params[o] + params[16 + o]);
  }
  float su[16], sq[16];
  #pragma unroll
  for (int o = 0; o < 16; ++o){
    float acc = b2[o];
    #pragma unroll
    for (int c = 0; c < 16; ++c) acc = fmaf(w2[o*16 + c], tv[c], acc);
    su[o] = acc; sq[o] = acc * acc;
  }
  reduce16(su, sq, partials);
}

// ---------------------------------------------------------------------------
// K3: recompute p2, apply bn2+lrelu, write p (bf16)  [channel = b*16+o]
// ---------------------------------------------------------------------------
__global__ __launch_bounds__(256) void k_prep(const uint8_t* __restrict__ xm,
                                              const float* __restrict__ w1,
                                              const float* __restrict__ b1,
                                              const float* __restrict__ w2,
                                              const float* __restrict__ b2,
                                              const float* __restrict__ params,
                                              bf16* __restrict__ p){
  int pix = blockIdx.x * 256 + threadIdx.x;
  int b = pix >> 18, hw = pix & (HW - 1);
  float x0 = xm[(b * 3 + 0) * HW + hw] * 0.0625f;
  float x1 = xm[(b * 3 + 1) * HW + hw] * 0.0625f;
  float x2 = xm[(b * 3 + 2) * HW + hw] * 0.0625f;
  float tv[16];
  #pragma unroll
  for (int o = 0; o < 16; ++o){
    float v = b1[o] + w1[o*3]*x0 + w1[o*3+1]*x1 + w1[o*3+2]*x2;
    tv[o] = lrelu(v * params[o] + params[16 + o]);
  }
  #pragma unroll
  for (int o = 0; o < 16; ++o){
    float acc = b2[o];
    #pragma unroll
    for (int c = 0; c < 16; ++c) acc = fmaf(w2[o*16 + c], tv[c], acc);
    float v = lrelu(acc * params[32 + o] + params[48 + o]);
    p[(b * 16 + o) * HW + hw] = f2b(v);
  }
}

// ---------------------------------------------------------------------------
// depthwise 3x3, zero-pad SAME
// ---------------------------------------------------------------------------
__device__ __forceinline__ float conv9(const bf16* __restrict__ plane, int h, int w,
                                       const float* wf){
  float acc = 0.0f;
  #pragma unroll
  for (int dy = 0; dy < 3; ++dy){
    int hh = h + dy - 1;
    if ((unsigned)hh >= 512u) continue;
    const bf16* row = plane + hh * 512;
    #pragma unroll
    for (int dx = 0; dx < 3; ++dx){
      int wc = w + dx - 1;
      if ((unsigned)wc >= 512u) continue;
      acc = fmaf(wf[dy*3 + dx], b2f(row[wc]), acc);
    }
  }
  return acc;
}

__device__ __forceinline__ void reduce2(float s, float q, float* __restrict__ partials){
  __shared__ float l2[2];
  int tid = threadIdx.x;
  if (tid < 2) l2[tid] = 0.0f;
  __syncthreads();
  #pragma unroll
  for (int off = 32; off >= 1; off >>= 1){
    s += __shfl_xor(s, off);
    q += __shfl_xor(q, off);
  }
  if ((tid & 63) == 0){ atomicAdd(&l2[0], s); atomicAdd(&l2[1], q); }
  __syncthreads();
  if (tid < 2) partials[blockIdx.x * 2 + tid] = l2[tid];
}

// ---------------------------------------------------------------------------
// A: conv stats only. block = one (b,f,h) row, 256 thr x 2 px. grid 16384.
// ---------------------------------------------------------------------------
__global__ __launch_bounds__(256) void k_convstat(const bf16* __restrict__ d,
                                                  const float* __restrict__ dw,
                                                  float* __restrict__ partials){
  int bid = blockIdx.x;
  int h = bid & 511, f = (bid >> 9) & 15, b = bid >> 13;
  int tid = threadIdx.x;
  const bf16* plane = d + (b * 16 + f) * HW;
  float wf[9];
  #pragma unroll
  for (int i = 0; i < 9; ++i) wf[i] = dw[f * 9 + i];
  float s = 0.0f, q = 0.0f;
  #pragma unroll
  for (int px = 0; px < 2; ++px){
    float acc = conv9(plane, h, tid + px * 256, wf);
    s += acc; q += acc * acc;
  }
  reduce2(s, q, partials);
}

// ---------------------------------------------------------------------------
// B: recompute conv, apply bnC+lrelu, write d_t (bf16), stats of d_t
// ---------------------------------------------------------------------------
__global__ __launch_bounds__(256) void k_bnwrite(const bf16* __restrict__ din,
                                                 const float* __restrict__ dw,
                                                 const float* __restrict__ params,
                                                 bf16* __restrict__ dout,
                                                 float* __restrict__ partials){
  int bid = blockIdx.x;
  int h = bid & 511, f = (bid >> 9) & 15, b = bid >> 13;
  int tid = threadIdx.x;
  const bf16* plane = din + (b * 16 + f) * HW;
  bf16* oplane = dout + (b * 16 + f) * HW + h * 512;
  float wf[9];
  #pragma unroll
  for (int i = 0; i < 9; ++i) wf[i] = dw[f * 9 + i];
  float sc = params[64 + f], sh = params[80 + f];
  float s = 0.0f, q = 0.0f;
  #pragma unroll
  for (int px = 0; px < 2; ++px){
    int w = tid + px * 256;
    float acc = conv9(plane, h, w, wf);
    float v = lrelu(acc * sc + sh);
    oplane[w] = f2b(v);
    s += v; q += v * v;
  }
  reduce2(s, q, partials);
}

// ---------------------------------------------------------------------------
// finalize kernels (256 threads, LDS tree)
// ---------------------------------------------------------------------------
__global__ __launch_bounds__(256) void k_fin_bn32(const float* __restrict__ partials,
                                                  const float* __restrict__ g,
                                                  const float* __restrict__ bb,
                                                  float* __restrict__ params,
                                                  int offS, int offT){
  int tid = threadIdx.x;
  int o = tid & 15, c = tid >> 4;
  double S = 0.0, Q = 0.0;
  for (int i = c * 128; i < (c + 1) * 128; ++i){
    S += (double)partials[i * 32 + o];
    Q += (double)partials[i * 32 + 16 + o];
  }
  __shared__ double lS[256], lQ[256];
  lS[tid] = S; lQ[tid] = Q; __syncthreads();
  for (int st = 8; st >= 1; st >>= 1){
    if (c < st){ lS[tid] += lS[tid + st * 16]; lQ[tid] += lQ[tid + st * 16]; }
    __syncthreads();
  }
  if (tid < 16){
    double m = lS[tid] / 524288.0;
    double v = lQ[tid] / 524288.0 - m * m;
    float sc = g[tid] / sqrtf((float)v + EPSF);
    params[offS + tid] = sc;
    params[offT + tid] = bb[tid] - (float)m * sc;
  }
}

__device__ __forceinline__ void gatherA(const float* __restrict__ partials, int o, int c,
                                        double& S, double& Q){
  for (int li = c * 64; li < (c + 1) * 64; ++li){
    int b2 = li >> 9, h = li & 511;
    int idx = (((b2 * 16 + o) << 9) + h) * 2;
    S += (double)partials[idx];
    Q += (double)partials[idx + 1];
  }
}

__global__ __launch_bounds__(256) void k_fin_bnA(const float* __restrict__ partials,
                                                 const float* __restrict__ g,
                                                 const float* __restrict__ bb,
                                                 float* __restrict__ params){
  int tid = threadIdx.x;
  int o = tid & 15, c = tid >> 4;
  double S = 0.0, Q = 0.0;
  gatherA(partials, o, c, S, Q);
  __shared__ double lS[256], lQ[256];
  lS[tid] = S; lQ[tid] = Q; __syncthreads();
  for (int st = 8; st >= 1; st >>= 1){
    if (c < st){ lS[tid] += lS[tid + st * 16]; lQ[tid] += lQ[tid + st * 16]; }
    __syncthreads();
  }
  if (tid < 16){
    double m = lS[tid] / 524288.0;
    double v = lQ[tid] / 524288.0 - m * m;
    float sc = g[tid] / sqrtf((float)v + EPSF);
    params[64 + tid] = sc;
    params[80 + tid] = bb[tid] - (float)m * sc;
  }
}

__global__ __launch_bounds__(256) void k_fin_dA(const float* __restrict__ partials,
                                                const float* __restrict__ ww,
                                                const float* __restrict__ gw,
                                                const float* __restrict__ bw,
                                                const float* __restrict__ wh,
                                                const float* __restrict__ gh,
                                                const float* __restrict__ bh,
                                                float* __restrict__ params, int t){
  int tid = threadIdx.x;
  int o = tid & 15, c = tid >> 4;
  double S = 0.0, Q = 0.0;
  gatherA(partials, o, c, S, Q);
  __shared__ double lS[256], lQ[256];
  lS[tid] = S; lQ[tid] = Q; __syncthreads();
  for (int st = 8; st >= 1; st >>= 1){
    if (c < st){ lS[tid] += lS[tid + st * 16]; lQ[tid] += lQ[tid + st * 16]; }
    __syncthreads();
  }
  if (tid < 16){
    float m = (float)(lS[tid] / 524288.0);
    float v = (float)(lQ[tid] / 524288.0) - m * m;
    float sw = ww[tid] * gw[tid] / sqrtf(ww[tid] * ww[tid] * v + EPSF);
    float tw = bw[tid] - m * sw;
    float s2 = wh[tid] * gh[tid] / sqrtf(wh[tid] * wh[tid] * v + EPSF);
    float t2 = bh[tid] - m * s2;
    int base = 96 + t * 64;
    params[base + tid]      = sw;
    params[base + 16 + tid] = tw;
    params[base + 32 + tid] = s2;
    params[base + 48 + tid] = t2;
  }
}

// ---------------------------------------------------------------------------
// F: assemble out[b_out, c'] = p_flat[c'] + sum_t lrelu(d_t[b_out, c'&15]*s+t)
// thread = one (f, hw); writes 4 outputs. grid 16384 x 256.
// ---------------------------------------------------------------------------
__global__ __launch_bounds__(256) void k_final(const bf16* __restrict__ p,
                                               const bf16* __restrict__ d1,
                                               const bf16* __restrict__ d2,
                                               const bf16* __restrict__ d3,
                                               const bf16* __restrict__ d4,
                                               const bf16* __restrict__ d5,
                                               const float* __restrict__ params,
                                               float* __restrict__ out){
  int idx = blockIdx.x * 256 + threadIdx.x;   // 0 .. 16*HW-1
  int f = idx >> 18, hw = idx & (HW - 1);
  int fo = f * HW + hw;
  int f1 = (16 + f) * HW + hw;
  float pf = b2f(p[fo]);
  float pg = b2f(p[f1]);
  float a00 = pf, a01 = pg, a10 = pf, a11 = pg;
  const bf16* dptrs[5] = {d1, d2, d3, d4, d5};
  #pragma unroll
  for (int t = 0; t < 5; ++t){
    const bf16* dp = dptrs[t];
    float dv0 = b2f(dp[fo]);
    float dv1 = b2f(dp[f1]);
    float sw = params[96 + t*64 + f],      tw = params[96 + t*64 + 16 + f];
    float sh = params[96 + t*64 + 32 + f], th = params[96 + t*64 + 48 + f];
    a00 += lrelu(fmaf(dv0, sw, tw));
    a01 += lrelu(fmaf(dv0, sh, th));
    a10 += lrelu(fmaf(dv1, sw, tw));
    a11 += lrelu(fmaf(dv1, sh, th));
  }
  out[f * HW + hw]        = a00;
  out[(16 + f) * HW + hw] = a01;
  out[(32 + f) * HW + hw] = a10;
  out[(48 + f) * HW + hw] = a11;
}

// ---------------------------------------------------------------------------
extern "C" void kernel_launch(void* const* d_in, const int* in_sizes, int n_in,
                              void* d_out, int out_size, void* d_ws, size_t ws_size,
                              hipStream_t stream){
  (void)in_sizes; (void)n_in; (void)out_size;
  const float* x   = (const float*)d_in[0];
  const float* w1  = (const float*)d_in[1];
  const float* b1  = (const float*)d_in[2];
  const float* g1  = (const float*)d_in[3];
  const float* be1 = (const float*)d_in[4];
  const float* w2  = (const float*)d_in[5];
  const float* b2  = (const float*)d_in[6];
  const float* g2  = (const float*)d_in[7];
  const float* be2 = (const float*)d_in[8];
  const float* dw  = (const float*)d_in[9];
  const float* gd  = (const float*)d_in[10];
  const float* bd  = (const float*)d_in[11];
  const float* ww  = (const float*)d_in[12];
  const float* gw  = (const float*)d_in[13];
  const float* bw  = (const float*)d_in[14];
  const float* wh  = (const float*)d_in[15];
  const float* gh  = (const float*)d_in[16];
  const float* bh  = (const float*)d_in[17];
  float* out = (float*)d_out;

  char* ws = (char*)d_ws;
  size_t off = 0;
  auto alloc = [&](size_t sz) -> void* {
    void* ptr = ws + off;
    off = (off + sz + 4095) & ~(size_t)4095;
    return ptr;
  };
  uint8_t* qpad     = (uint8_t*)alloc((size_t)6 * 522 * 528);
  uint8_t* xm       = (uint8_t*)alloc((size_t)6 * HW);
  bf16*    p        = (bf16*)   alloc((size_t)32 * HW * 2);
  bf16*    dbuf[5];
  for (int i = 0; i < 5; ++i) dbuf[i] = (bf16*)alloc((size_t)32 * HW * 2);
  float*   partials = (float*)  alloc((size_t)2048 * 32 * 4);
  float*   params   = (float*)  alloc(4096);
  if (ws_size < off) return;   // workspace too small: fail visibly (untouched out)

  k_quant_pad<<<dim3((6*522*522 + 255)/256), dim3(256), 0, stream>>>(x, qpad);
  k_mode     <<<dim3(768),   dim3(256), 0, stream>>>(qpad, xm);
  k_stats1   <<<dim3(2048),  dim3(256), 0, stream>>>(xm, w1, b1, partials);
  k_fin_bn32 <<<dim3(1),     dim3(256), 0, stream>>>(partials, g1, be1, params, 0, 16);
  k_stats2   <<<dim3(2048),  dim3(256), 0, stream>>>(xm, w1, b1, w2, b2, params, partials);
  k_fin_bn32 <<<dim3(1),     dim3(256), 0, stream>>>(partials, g2, be2, params, 32, 48);
  k_prep     <<<dim3(2048),  dim3(256), 0, stream>>>(xm, w1, b1, w2, b2, params, p);

  const bf16* dcur = p;
  for (int t = 0; t < 5; ++t){
    k_convstat<<<dim3(16384), dim3(256), 0, stream>>>(dcur, dw, partials);
    k_fin_bnA <<<dim3(1),     dim3(256), 0, stream>>>(partials, gd, bd, params);
    k_bnwrite <<<dim3(16384), dim3(256), 0, stream>>>(dcur, dw, params, dbuf[t], partials);
    k_fin_dA  <<<dim3(1),     dim3(256), 0, stream>>>(partials, ww, gw, bw, wh, gh, bh, params, t);
    dcur = dbuf[t];
  }
  k_final<<<dim3(16384), dim3(256), 0, stream>>>(p, dbuf[0], dbuf[1], dbuf[2],
                                                 dbuf[3], dbuf[4], params, out);
}

// Round 3
// 375.970 us; speedup vs baseline: 2.1630x; 2.1630x over previous
//
#include <hip/hip_runtime.h>
#include <hip/hip_bf16.h>
#include <stdint.h>
#include <stddef.h>

#define HW 262144          // 512*512
#define EPSF 1e-5f

typedef __hip_bfloat16 bf16;

__device__ __forceinline__ float us2f(uint32_t u){
  union { uint32_t i; float f; } c; c.i = u << 16; return c.f;
}
__device__ __forceinline__ ushort f2bu(float v){
  union { bf16 h; ushort u; } c; c.h = __float2bfloat16(v); return c.u;
}
__device__ __forceinline__ float lrelu(float v){ return v > 0.0f ? v : 0.01f * v; }

// ---------------------------------------------------------------------------
// K0a: quantize x to level k = rint(x*255/16), materialize reflect-padded u8
// plane [6][522 rows][pitch 528]
// ---------------------------------------------------------------------------
__global__ __launch_bounds__(256) void k_quant_pad(const float* __restrict__ x,
                                                   uint8_t* __restrict__ qpad){
  int idx = blockIdx.x * 256 + threadIdx.x;
  if (idx >= 6 * 522 * 522) return;
  int pw = idx % 522; int t = idx / 522; int ph = t % 522; int img = t / 522;
  int h = ph - 5; h = h < 0 ? -h : h; if (h > 511) h = 1022 - h;
  int w = pw - 5; w = w < 0 ? -w : w; if (w > 511) w = 1022 - w;
  float v = x[img * HW + h * 512 + w];
  int k = (int)rintf((v * 255.0f) / 16.0f);   // round-half-even, matches jnp.round
  qpad[img * (522 * 528) + ph * 528 + pw] = (uint8_t)k;
}

// ---------------------------------------------------------------------------
// K0b: 11x11 mode filter. Thread = 8 consecutive output pixels in one row.
// Rows loaded as 5 dwords into registers; sliding 17-bin histogram packed
// 8-bit into 5 u32 registers. Block 256 = 4 rows x 64 threads. Grid 768.
// ---------------------------------------------------------------------------
__global__ __launch_bounds__(256) void k_mode(const uint8_t* __restrict__ qpad,
                                              uint8_t* __restrict__ xm){
  int tid = threadIdx.x;
  int img = blockIdx.x >> 7;
  int h   = ((blockIdx.x & 127) << 2) + (tid >> 6);
  int w0  = (tid & 63) << 3;
  const uint8_t* base = qpad + img * (522 * 528) + h * 528 + w0;
  uint32_t rv[11][5];
  #pragma unroll
  for (int r = 0; r < 11; ++r){
    const uint32_t* rp = (const uint32_t*)(base + r * 528);   // 8B aligned
    uint2 a  = *(const uint2*)rp;
    uint2 bq = *(const uint2*)(rp + 2);
    uint32_t e = rp[4];
    rv[r][0] = a.x; rv[r][1] = a.y; rv[r][2] = bq.x; rv[r][3] = bq.y; rv[r][4] = e;
  }
  uint32_t c0 = 0, c1 = 0, c2 = 0, c3 = 0, c4 = 0;
#define BYTEV(r, j) ((rv[r][(j) >> 2] >> (((j) & 3) << 3)) & 0xffu)
#define HINC(q) { uint32_t inc_ = 1u << (((q) & 3u) << 3); uint32_t rr_ = (q) >> 2; \
    c0 += (rr_==0u)?inc_:0u; c1 += (rr_==1u)?inc_:0u; c2 += (rr_==2u)?inc_:0u; \
    c3 += (rr_==3u)?inc_:0u; c4 += (rr_==4u)?inc_:0u; }
#define HDEC(q) { uint32_t inc_ = 1u << (((q) & 3u) << 3); uint32_t rr_ = (q) >> 2; \
    c0 -= (rr_==0u)?inc_:0u; c1 -= (rr_==1u)?inc_:0u; c2 -= (rr_==2u)?inc_:0u; \
    c3 -= (rr_==3u)?inc_:0u; c4 -= (rr_==4u)?inc_:0u; }
  #pragma unroll
  for (int r = 0; r < 11; ++r){
    #pragma unroll
    for (int j = 0; j < 11; ++j){ uint32_t q = BYTEV(r, j); HINC(q); }
  }
  uint64_t packed = 0;
  #pragma unroll
  for (int s = 0; s < 8; ++s){
    int best = 0, bc = -1;
#define CHK(l, reg, sh) { int cnt = (int)(((reg) >> (sh)) & 0xffu); if (cnt > bc){ bc = cnt; best = (l); } }
    CHK(0,c0,0)  CHK(1,c0,8)  CHK(2,c0,16)  CHK(3,c0,24)
    CHK(4,c1,0)  CHK(5,c1,8)  CHK(6,c1,16)  CHK(7,c1,24)
    CHK(8,c2,0)  CHK(9,c2,8)  CHK(10,c2,16) CHK(11,c2,24)
    CHK(12,c3,0) CHK(13,c3,8) CHK(14,c3,16) CHK(15,c3,24)
    CHK(16,c4,0)
#undef CHK
    packed |= ((uint64_t)(uint8_t)best) << (8 * s);
    if (s < 7){
      #pragma unroll
      for (int r = 0; r < 11; ++r){
        uint32_t qo = BYTEV(r, s);      HDEC(qo);
        uint32_t qn = BYTEV(r, s + 11); HINC(qn);
      }
    }
  }
#undef HINC
#undef HDEC
#undef BYTEV
  *(uint64_t*)(xm + img * HW + h * 512 + w0) = packed;
}

// ---------------------------------------------------------------------------
// block reduction of per-thread su[16]/sq[16] -> partials[block][32]
// ---------------------------------------------------------------------------
__device__ __forceinline__ void reduce16(float* su, float* sq, float* __restrict__ partials){
  __shared__ float lsum[32];
  int tid = threadIdx.x;
  if (tid < 32) lsum[tid] = 0.0f;
  __syncthreads();
  #pragma unroll
  for (int o = 0; o < 16; ++o){
    float s = su[o], q = sq[o];
    #pragma unroll
    for (int off = 32; off >= 1; off >>= 1){
      s += __shfl_xor(s, off);
      q += __shfl_xor(q, off);
    }
    if ((tid & 63) == 0){ atomicAdd(&lsum[o], s); atomicAdd(&lsum[16 + o], q); }
  }
  __syncthreads();
  if (tid < 32) partials[blockIdx.x * 32 + tid] = lsum[tid];
}

// ---------------------------------------------------------------------------
// K1: stats of p1 = conv1x1(xm). 4 px/thread. grid 512 x 256.
// ---------------------------------------------------------------------------
__global__ __launch_bounds__(256) void k_stats1(const uint8_t* __restrict__ xm,
                                                const float* __restrict__ w1,
                                                const float* __restrict__ b1,
                                                float* __restrict__ partials){
  int t0 = (blockIdx.x * 256 + threadIdx.x) << 2;
  int b = t0 >> 18, hw = t0 & (HW - 1);
  uint32_t q0 = *(const uint32_t*)(xm + (b * 3 + 0) * HW + hw);
  uint32_t q1 = *(const uint32_t*)(xm + (b * 3 + 1) * HW + hw);
  uint32_t q2 = *(const uint32_t*)(xm + (b * 3 + 2) * HW + hw);
  float su[16], sq[16];
  #pragma unroll
  for (int o = 0; o < 16; ++o){ su[o] = 0.0f; sq[o] = 0.0f; }
  #pragma unroll
  for (int px = 0; px < 4; ++px){
    float x0 = (float)((q0 >> (8 * px)) & 0xffu) * 0.0625f;
    float x1 = (float)((q1 >> (8 * px)) & 0xffu) * 0.0625f;
    float x2 = (float)((q2 >> (8 * px)) & 0xffu) * 0.0625f;
    #pragma unroll
    for (int o = 0; o < 16; ++o){
      float v = b1[o] + w1[o*3]*x0 + w1[o*3+1]*x1 + w1[o*3+2]*x2;
      su[o] += v; sq[o] += v * v;
    }
  }
  reduce16(su, sq, partials);
}

// ---------------------------------------------------------------------------
// K2: recompute p1, bn1+lrelu, p2 = conv1x1, stats of p2. 4 px/thread.
// ---------------------------------------------------------------------------
__global__ __launch_bounds__(256) void k_stats2(const uint8_t* __restrict__ xm,
                                                const float* __restrict__ w1,
                                                const float* __restrict__ b1,
                                                const float* __restrict__ w2,
                                                const float* __restrict__ b2,
                                                const float* __restrict__ params,
                                                float* __restrict__ partials){
  int t0 = (blockIdx.x * 256 + threadIdx.x) << 2;
  int b = t0 >> 18, hw = t0 & (HW - 1);
  uint32_t q0 = *(const uint32_t*)(xm + (b * 3 + 0) * HW + hw);
  uint32_t q1 = *(const uint32_t*)(xm + (b * 3 + 1) * HW + hw);
  uint32_t q2 = *(const uint32_t*)(xm + (b * 3 + 2) * HW + hw);
  float tv[4][16];
  #pragma unroll
  for (int px = 0; px < 4; ++px){
    float x0 = (float)((q0 >> (8 * px)) & 0xffu) * 0.0625f;
    float x1 = (float)((q1 >> (8 * px)) & 0xffu) * 0.0625f;
    float x2 = (float)((q2 >> (8 * px)) & 0xffu) * 0.0625f;
    #pragma unroll
    for (int o = 0; o < 16; ++o){
      float v = b1[o] + w1[o*3]*x0 + w1[o*3+1]*x1 + w1[o*3+2]*x2;
      tv[px][o] = lrelu(v * params[o] + params[16 + o]);
    }
  }
  float su[16], sq[16];
  #pragma unroll
  for (int o = 0; o < 16; ++o){ su[o] = 0.0f; sq[o] = 0.0f; }
  #pragma unroll
  for (int o = 0; o < 16; ++o){
    #pragma unroll
    for (int px = 0; px < 4; ++px){
      float acc = b2[o];
      #pragma unroll
      for (int c = 0; c < 16; ++c) acc = fmaf(w2[o*16 + c], tv[px][c], acc);
      su[o] += acc; sq[o] += acc * acc;
    }
  }
  reduce16(su, sq, partials);
}

// ---------------------------------------------------------------------------
// K3: recompute p2, bn2+lrelu, write p (bf16). 4 px/thread.
// ---------------------------------------------------------------------------
__global__ __launch_bounds__(256) void k_prep(const uint8_t* __restrict__ xm,
                                              const float* __restrict__ w1,
                                              const float* __restrict__ b1,
                                              const float* __restrict__ w2,
                                              const float* __restrict__ b2,
                                              const float* __restrict__ params,
                                              bf16* __restrict__ p){
  int t0 = (blockIdx.x * 256 + threadIdx.x) << 2;
  int b = t0 >> 18, hw = t0 & (HW - 1);
  uint32_t q0 = *(const uint32_t*)(xm + (b * 3 + 0) * HW + hw);
  uint32_t q1 = *(const uint32_t*)(xm + (b * 3 + 1) * HW + hw);
  uint32_t q2 = *(const uint32_t*)(xm + (b * 3 + 2) * HW + hw);
  float tv[4][16];
  #pragma unroll
  for (int px = 0; px < 4; ++px){
    float x0 = (float)((q0 >> (8 * px)) & 0xffu) * 0.0625f;
    float x1 = (float)((q1 >> (8 * px)) & 0xffu) * 0.0625f;
    float x2 = (float)((q2 >> (8 * px)) & 0xffu) * 0.0625f;
    #pragma unroll
    for (int o = 0; o < 16; ++o){
      float v = b1[o] + w1[o*3]*x0 + w1[o*3+1]*x1 + w1[o*3+2]*x2;
      tv[px][o] = lrelu(v * params[o] + params[16 + o]);
    }
  }
  #pragma unroll
  for (int o = 0; o < 16; ++o){
    uint32_t w01 = 0, w23 = 0;
    #pragma unroll
    for (int px = 0; px < 4; ++px){
      float acc = b2[o];
      #pragma unroll
      for (int c = 0; c < 16; ++c) acc = fmaf(w2[o*16 + c], tv[px][c], acc);
      float v = lrelu(acc * params[32 + o] + params[48 + o]);
      uint32_t bits = (uint32_t)f2bu(v);
      if (px == 0) w01 = bits;
      else if (px == 1) w01 |= bits << 16;
      else if (px == 2) w23 = bits;
      else w23 |= bits << 16;
    }
    uint2 ov; ov.x = w01; ov.y = w23;
    *(uint2*)((ushort*)p + (b * 16 + o) * HW + hw) = ov;
  }
}

// ---------------------------------------------------------------------------
// row loader for depthwise conv: 10 values (cols w0-1 .. w0+8), zero-padded
// ---------------------------------------------------------------------------
__device__ __forceinline__ void load_row10(const ushort* __restrict__ rp, int w0, float* v){
  uint4 cc = *(const uint4*)(rp + w0);                     // 16B aligned
  uint32_t l = (w0 == 0)   ? 0u : (uint32_t)rp[w0 - 1];
  uint32_t r = (w0 == 504) ? 0u : (uint32_t)rp[w0 + 8];
  v[0] = us2f(l);
  v[1] = us2f(cc.x & 0xffffu); v[2] = us2f(cc.x >> 16);
  v[3] = us2f(cc.y & 0xffffu); v[4] = us2f(cc.y >> 16);
  v[5] = us2f(cc.z & 0xffffu); v[6] = us2f(cc.z >> 16);
  v[7] = us2f(cc.w & 0xffffu); v[8] = us2f(cc.w >> 16);
  v[9] = us2f(r);
}

__device__ __forceinline__ void zero_row10(float* v){
  #pragma unroll
  for (int j = 0; j < 10; ++j) v[j] = 0.0f;
}

__device__ __forceinline__ void reduce2(float s, float q, float* __restrict__ partials){
  __shared__ float l2[2];
  int tid = threadIdx.x;
  if (tid < 2) l2[tid] = 0.0f;
  __syncthreads();
  #pragma unroll
  for (int off = 32; off >= 1; off >>= 1){
    s += __shfl_xor(s, off);
    q += __shfl_xor(q, off);
  }
  if ((tid & 63) == 0){ atomicAdd(&l2[0], s); atomicAdd(&l2[1], q); }
  __syncthreads();
  if (tid < 2) partials[blockIdx.x * 2 + tid] = l2[tid];
}

// ---------------------------------------------------------------------------
// A: conv stats only. 8 px/thread. block = (plane, 4-row group). grid 4096.
// ---------------------------------------------------------------------------
__global__ __launch_bounds__(256) void k_convstat(const bf16* __restrict__ d,
                                                  const float* __restrict__ dw,
                                                  float* __restrict__ P1){
  int bid = blockIdx.x;
  int plane = bid >> 7, rg = bid & 127;
  int f = plane & 15;
  int tid = threadIdx.x;
  int h  = (rg << 2) + (tid >> 6);
  int w0 = (tid & 63) << 3;
  const ushort* pl = (const ushort*)d + plane * HW;
  float wf[9];
  #pragma unroll
  for (int i = 0; i < 9; ++i) wf[i] = dw[f * 9 + i];
  float v[3][10];
  #pragma unroll
  for (int dy = 0; dy < 3; ++dy){
    int row = h + dy - 1;
    if ((unsigned)row < 512u) load_row10(pl + row * 512, w0, v[dy]);
    else zero_row10(v[dy]);
  }
  float s = 0.0f, q = 0.0f;
  #pragma unroll
  for (int k = 0; k < 8; ++k){
    float acc = 0.0f;
    #pragma unroll
    for (int dy = 0; dy < 3; ++dy)
      #pragma unroll
      for (int dx = 0; dx < 3; ++dx)
        acc = fmaf(wf[dy*3 + dx], v[dy][k + dx], acc);
    s += acc; q += acc * acc;
  }
  reduce2(s, q, P1);
}

// ---------------------------------------------------------------------------
// B: recompute conv, bnC+lrelu, write d_t (bf16), stats of d_t. 8 px/thread.
// ---------------------------------------------------------------------------
__global__ __launch_bounds__(256) void k_bnwrite(const bf16* __restrict__ din,
                                                 const float* __restrict__ dw,
                                                 const float* __restrict__ params,
                                                 bf16* __restrict__ dout,
                                                 float* __restrict__ P2){
  int bid = blockIdx.x;
  int plane = bid >> 7, rg = bid & 127;
  int f = plane & 15;
  int tid = threadIdx.x;
  int h  = (rg << 2) + (tid >> 6);
  int w0 = (tid & 63) << 3;
  const ushort* pl = (const ushort*)din + plane * HW;
  float wf[9];
  #pragma unroll
  for (int i = 0; i < 9; ++i) wf[i] = dw[f * 9 + i];
  float sc = params[64 + f], sh = params[80 + f];
  float v[3][10];
  #pragma unroll
  for (int dy = 0; dy < 3; ++dy){
    int row = h + dy - 1;
    if ((unsigned)row < 512u) load_row10(pl + row * 512, w0, v[dy]);
    else zero_row10(v[dy]);
  }
  float s = 0.0f, q = 0.0f;
  uint32_t ob[4];
  #pragma unroll
  for (int k = 0; k < 8; ++k){
    float acc = 0.0f;
    #pragma unroll
    for (int dy = 0; dy < 3; ++dy)
      #pragma unroll
      for (int dx = 0; dx < 3; ++dx)
        acc = fmaf(wf[dy*3 + dx], v[dy][k + dx], acc);
    float vv = lrelu(acc * sc + sh);
    uint32_t bits = (uint32_t)f2bu(vv);
    if ((k & 1) == 0) ob[k >> 1] = bits; else ob[k >> 1] |= bits << 16;
    s += vv; q += vv * vv;
  }
  uint4 ov; ov.x = ob[0]; ov.y = ob[1]; ov.z = ob[2]; ov.w = ob[3];
  *(uint4*)((ushort*)dout + plane * HW + h * 512 + w0) = ov;
  reduce2(s, q, P2);
}

// ---------------------------------------------------------------------------
// finalize: prepare-stage BN (512-block x 32 partials layout)
// ---------------------------------------------------------------------------
__global__ __launch_bounds__(256) void k_fin_prep(const float* __restrict__ partials,
                                                  const float* __restrict__ g,
                                                  const float* __restrict__ bb,
                                                  float* __restrict__ params,
                                                  int offS, int offT){
  int tid = threadIdx.x;
  int o = tid & 15, c = tid >> 4;
  double S = 0.0, Q = 0.0;
  for (int i = c * 32; i < (c + 1) * 32; ++i){
    S += (double)partials[i * 32 + o];
    Q += (double)partials[i * 32 + 16 + o];
  }
  __shared__ double lS[256], lQ[256];
  lS[tid] = S; lQ[tid] = Q; __syncthreads();
  for (int st = 8; st >= 1; st >>= 1){
    if (c < st){ lS[tid] += lS[tid + st * 16]; lQ[tid] += lQ[tid + st * 16]; }
    __syncthreads();
  }
  if (tid < 16){
    double m = lS[tid] / 524288.0;
    double v = lQ[tid] / 524288.0 - m * m;
    float sc = g[tid] / sqrtf((float)v + EPSF);
    params[offS + tid] = sc;
    params[offT + tid] = bb[tid] - (float)m * sc;
  }
}

// gather for 4096-block x 2 partials layout: channel o -> 256 entries
__device__ __forceinline__ void gather256(const float* __restrict__ P, int o, int c,
                                          double& S, double& Q){
  #pragma unroll
  for (int i = 0; i < 16; ++i){
    int li = c * 16 + i;
    int b = li >> 7, rg = li & 127;
    int blk = ((b * 16 + o) << 7) + rg;
    S += (double)P[blk * 2];
    Q += (double)P[blk * 2 + 1];
  }
}

__device__ __forceinline__ void tree16(double* lS, double* lQ, int tid, int c){
  __syncthreads();
  for (int st = 8; st >= 1; st >>= 1){
    if (c < st){ lS[tid] += lS[tid + st * 16]; lQ[tid] += lQ[tid + st * 16]; }
    __syncthreads();
  }
}

// ---------------------------------------------------------------------------
// merged loop finalize: bnA (conv BN params) from P1; dA (wdt/hgt affine
// params for iteration tdA) from P2.
// ---------------------------------------------------------------------------
__global__ __launch_bounds__(256) void k_finloop(const float* __restrict__ P1,
                                                 const float* __restrict__ P2,
                                                 const float* __restrict__ gd,
                                                 const float* __restrict__ bd,
                                                 const float* __restrict__ ww,
                                                 const float* __restrict__ gw,
                                                 const float* __restrict__ bw,
                                                 const float* __restrict__ wh,
                                                 const float* __restrict__ gh,
                                                 const float* __restrict__ bh,
                                                 float* __restrict__ params,
                                                 int tdA, int do_bnA){
  __shared__ double lS[256], lQ[256];
  int tid = threadIdx.x;
  int o = tid & 15, c = tid >> 4;
  if (do_bnA){
    double S = 0.0, Q = 0.0;
    gather256(P1, o, c, S, Q);
    lS[tid] = S; lQ[tid] = Q;
    tree16(lS, lQ, tid, c);
    if (tid < 16){
      double m = lS[tid] / 524288.0;
      double v = lQ[tid] / 524288.0 - m * m;
      float sc = gd[tid] / sqrtf((float)v + EPSF);
      params[64 + tid] = sc;
      params[80 + tid] = bd[tid] - (float)m * sc;
    }
    __syncthreads();
  }
  if (tdA >= 0){
    double S = 0.0, Q = 0.0;
    gather256(P2, o, c, S, Q);
    lS[tid] = S; lQ[tid] = Q;
    tree16(lS, lQ, tid, c);
    if (tid < 16){
      float m = (float)(lS[tid] / 524288.0);
      float v = (float)(lQ[tid] / 524288.0) - m * m;
      float sw = ww[tid] * gw[tid] / sqrtf(ww[tid] * ww[tid] * v + EPSF);
      float tw = bw[tid] - m * sw;
      float s2 = wh[tid] * gh[tid] / sqrtf(wh[tid] * wh[tid] * v + EPSF);
      float t2 = bh[tid] - m * s2;
      int base = 96 + tdA * 64;
      params[base + tid]      = sw;
      params[base + 16 + tid] = tw;
      params[base + 32 + tid] = s2;
      params[base + 48 + tid] = t2;
    }
  }
}

// ---------------------------------------------------------------------------
// F: assemble out. 8 px/thread, all loads uint4, stores float4. grid 2048.
// ---------------------------------------------------------------------------
__device__ __forceinline__ void load8(const ushort* __restrict__ ptr, float* v){
  uint4 cc = *(const uint4*)ptr;
  v[0] = us2f(cc.x & 0xffffu); v[1] = us2f(cc.x >> 16);
  v[2] = us2f(cc.y & 0xffffu); v[3] = us2f(cc.y >> 16);
  v[4] = us2f(cc.z & 0xffffu); v[5] = us2f(cc.z >> 16);
  v[6] = us2f(cc.w & 0xffffu); v[7] = us2f(cc.w >> 16);
}

__global__ __launch_bounds__(256) void k_final(const bf16* __restrict__ p,
                                               const bf16* __restrict__ d1,
                                               const bf16* __restrict__ d2,
                                               const bf16* __restrict__ d3,
                                               const bf16* __restrict__ d4,
                                               const bf16* __restrict__ d5,
                                               const float* __restrict__ params,
                                               float* __restrict__ out){
  int gid = blockIdx.x * 256 + threadIdx.x;     // 0 .. 524287
  int f = gid >> 15;
  int hw = (gid & 32767) << 3;
  int fo = f * HW + hw;
  int f1 = (16 + f) * HW + hw;
  float pf[8], pg[8];
  load8((const ushort*)p + fo, pf);
  load8((const ushort*)p + f1, pg);
  float a00[8], a01[8], a10[8], a11[8];
  #pragma unroll
  for (int k = 0; k < 8; ++k){ a00[k] = pf[k]; a01[k] = pg[k]; a10[k] = pf[k]; a11[k] = pg[k]; }
  const bf16* dptrs[5] = {d1, d2, d3, d4, d5};
  #pragma unroll
  for (int t = 0; t < 5; ++t){
    const ushort* dp = (const ushort*)dptrs[t];
    float dv0[8], dv1[8];
    load8(dp + fo, dv0);
    load8(dp + f1, dv1);
    float sw = params[96 + t*64 + f],      tw = params[96 + t*64 + 16 + f];
    float sh = params[96 + t*64 + 32 + f], th = params[96 + t*64 + 48 + f];
    #pragma unroll
    for (int k = 0; k < 8; ++k){
      a00[k] += lrelu(fmaf(dv0[k], sw, tw));
      a01[k] += lrelu(fmaf(dv0[k], sh, th));
      a10[k] += lrelu(fmaf(dv1[k], sw, tw));
      a11[k] += lrelu(fmaf(dv1[k], sh, th));
    }
  }
  #pragma unroll
  for (int half = 0; half < 2; ++half){
    float4 v0 = { a00[half*4+0], a00[half*4+1], a00[half*4+2], a00[half*4+3] };
    float4 v1 = { a01[half*4+0], a01[half*4+1], a01[half*4+2], a01[half*4+3] };
    float4 v2 = { a10[half*4+0], a10[half*4+1], a10[half*4+2], a10[half*4+3] };
    float4 v3 = { a11[half*4+0], a11[half*4+1], a11[half*4+2], a11[half*4+3] };
    *(float4*)(out + f * HW + hw + half*4)        = v0;
    *(float4*)(out + (16 + f) * HW + hw + half*4) = v1;
    *(float4*)(out + (32 + f) * HW + hw + half*4) = v2;
    *(float4*)(out + (48 + f) * HW + hw + half*4) = v3;
  }
}

// ---------------------------------------------------------------------------
extern "C" void kernel_launch(void* const* d_in, const int* in_sizes, int n_in,
                              void* d_out, int out_size, void* d_ws, size_t ws_size,
                              hipStream_t stream){
  (void)in_sizes; (void)n_in; (void)out_size;
  const float* x   = (const float*)d_in[0];
  const float* w1  = (const float*)d_in[1];
  const float* b1  = (const float*)d_in[2];
  const float* g1  = (const float*)d_in[3];
  const float* be1 = (const float*)d_in[4];
  const float* w2  = (const float*)d_in[5];
  const float* b2  = (const float*)d_in[6];
  const float* g2  = (const float*)d_in[7];
  const float* be2 = (const float*)d_in[8];
  const float* dw  = (const float*)d_in[9];
  const float* gd  = (const float*)d_in[10];
  const float* bd  = (const float*)d_in[11];
  const float* ww  = (const float*)d_in[12];
  const float* gw  = (const float*)d_in[13];
  const float* bw  = (const float*)d_in[14];
  const float* wh  = (const float*)d_in[15];
  const float* gh  = (const float*)d_in[16];
  const float* bh  = (const float*)d_in[17];
  float* out = (float*)d_out;

  char* ws = (char*)d_ws;
  size_t off = 0;
  auto alloc = [&](size_t sz) -> void* {
    void* ptr = ws + off;
    off = (off + sz + 4095) & ~(size_t)4095;
    return ptr;
  };
  uint8_t* qpad  = (uint8_t*)alloc((size_t)6 * 522 * 528);
  uint8_t* xm    = (uint8_t*)alloc((size_t)6 * HW);
  bf16*    p     = (bf16*)   alloc((size_t)32 * HW * 2);
  bf16*    dbuf[5];
  for (int i = 0; i < 5; ++i) dbuf[i] = (bf16*)alloc((size_t)32 * HW * 2);
  float*   Pp     = (float*)  alloc((size_t)512 * 32 * 4);
  float*   P1     = (float*)  alloc((size_t)4096 * 2 * 4);
  float*   P2     = (float*)  alloc((size_t)4096 * 2 * 4);
  float*   params = (float*)  alloc(4096);
  if (ws_size < off) return;   // workspace too small: fail visibly (untouched out)

  k_quant_pad<<<dim3((6*522*522 + 255)/256), dim3(256), 0, stream>>>(x, qpad);
  k_mode     <<<dim3(768), dim3(256), 0, stream>>>(qpad, xm);
  k_stats1   <<<dim3(512), dim3(256), 0, stream>>>(xm, w1, b1, Pp);
  k_fin_prep <<<dim3(1),   dim3(256), 0, stream>>>(Pp, g1, be1, params, 0, 16);
  k_stats2   <<<dim3(512), dim3(256), 0, stream>>>(xm, w1, b1, w2, b2, params, Pp);
  k_fin_prep <<<dim3(1),   dim3(256), 0, stream>>>(Pp, g2, be2, params, 32, 48);
  k_prep     <<<dim3(512), dim3(256), 0, stream>>>(xm, w1, b1, w2, b2, params, p);

  const bf16* dcur = p;
  for (int t = 0; t < 5; ++t){
    k_convstat<<<dim3(4096), dim3(256), 0, stream>>>(dcur, dw, P1);
    k_finloop <<<dim3(1),    dim3(256), 0, stream>>>(P1, P2, gd, bd, ww, gw, bw,
                                                     wh, gh, bh, params, t - 1, 1);
    k_bnwrite <<<dim3(4096), dim3(256), 0, stream>>>(dcur, dw, params, dbuf[t], P2);
    dcur = dbuf[t];
  }
  k_finloop<<<dim3(1), dim3(256), 0, stream>>>(P1, P2, gd, bd, ww, gw, bw,
                                               wh, gh, bh, params, 4, 0);
  k_final<<<dim3(2048), dim3(256), 0, stream>>>(p, dbuf[0], dbuf[1], dbuf[2],
                                                dbuf[3], dbuf[4], params, out);
}

// Round 4
// 367.045 us; speedup vs baseline: 2.2156x; 1.0243x over previous
//
#include <hip/hip_runtime.h>
#include <hip/hip_bf16.h>
#include <stdint.h>
#include <stddef.h>

#define HW 262144          // 512*512
#define EPSF 1e-5f

typedef __hip_bfloat16 bf16;

__device__ __forceinline__ float us2f(uint32_t u){
  union { uint32_t i; float f; } c; c.i = u << 16; return c.f;
}
__device__ __forceinline__ ushort f2bu(float v){
  union { bf16 h; ushort u; } c; c.h = __float2bfloat16(v); return c.u;
}
__device__ __forceinline__ float lrelu(float v){ return v > 0.0f ? v : 0.01f * v; }
__device__ __forceinline__ uint32_t umax2(uint32_t a, uint32_t b){ return a > b ? a : b; }

// ---------------------------------------------------------------------------
// K0a: quantize x to level k = rint(x*255/16), materialize reflect-padded u8
// plane [6][522 rows][pitch 528]
// ---------------------------------------------------------------------------
__global__ __launch_bounds__(256) void k_quant_pad(const float* __restrict__ x,
                                                   uint8_t* __restrict__ qpad){
  int idx = blockIdx.x * 256 + threadIdx.x;
  if (idx >= 6 * 522 * 522) return;
  int pw = idx % 522; int t = idx / 522; int ph = t % 522; int img = t / 522;
  int h = ph - 5; h = h < 0 ? -h : h; if (h > 511) h = 1022 - h;
  int w = pw - 5; w = w < 0 ? -w : w; if (w > 511) w = 1022 - w;
  float v = x[img * HW + h * 512 + w];
  int k = (int)rintf((v * 255.0f) / 16.0f);   // round-half-even, matches jnp.round
  qpad[img * (522 * 528) + ph * 528 + pw] = (uint8_t)k;
}

// ---------------------------------------------------------------------------
// K0b: 11x11 mode filter. Block = 4 output rows x 64 threads x 8 px.
// Tile (14 rows x 528 B) staged in LDS via uint4; per-thread sliding 17-bin
// histogram packed 8-bit into 5 u32 registers, bytes read from LDS with
// immediate offsets (no big register array -> no spill). Argmax via packed
// keys (cnt<<5)|(16-lvl) + max tree (tie -> smallest level).
// ---------------------------------------------------------------------------
__global__ __launch_bounds__(256) void k_mode(const uint8_t* __restrict__ qpad,
                                              uint8_t* __restrict__ xm){
  __shared__ uint8_t tile[14 * 528];          // 7392 B
  int tid = threadIdx.x;
  int img = blockIdx.x >> 7;
  int h0  = (blockIdx.x & 127) << 2;          // first output row of block
  {
    const uint4* g4 = (const uint4*)(qpad + img * (522 * 528) + h0 * 528);
    uint4* t4 = (uint4*)tile;
    t4[tid] = g4[tid];                        // 0..255
    if (tid < 206) t4[tid + 256] = g4[tid + 256];   // 256..461 (462 total)
  }
  __syncthreads();
  int r4 = tid >> 6;                          // row within block 0..3
  int w0 = (tid & 63) << 3;                   // 0..504
  const uint8_t* base = tile + r4 * 528 + w0;
  uint32_t c0 = 0, c1 = 0, c2 = 0, c3 = 0, c4 = 0;
#define HINC(q) { uint32_t inc_ = 1u << (((q) & 3u) << 3); uint32_t rr_ = (q) >> 2; \
    c0 += (rr_==0u)?inc_:0u; c1 += (rr_==1u)?inc_:0u; c2 += (rr_==2u)?inc_:0u; \
    c3 += (rr_==3u)?inc_:0u; c4 += (rr_==4u)?inc_:0u; }
#define HDEC(q) { uint32_t inc_ = 1u << (((q) & 3u) << 3); uint32_t rr_ = (q) >> 2; \
    c0 -= (rr_==0u)?inc_:0u; c1 -= (rr_==1u)?inc_:0u; c2 -= (rr_==2u)?inc_:0u; \
    c3 -= (rr_==3u)?inc_:0u; c4 -= (rr_==4u)?inc_:0u; }
  #pragma unroll
  for (int r = 0; r < 11; ++r){
    #pragma unroll
    for (int j = 0; j < 11; ++j){ uint32_t q = base[r * 528 + j]; HINC(q); }
  }
  uint64_t packed = 0;
  #pragma unroll
  for (int s = 0; s < 8; ++s){
    // key(l) = (cnt<<5) | (16-l); max key -> max cnt, tie -> smallest level
#define KEY(reg, sh, l) (((((reg) >> (sh)) & 0xffu) << 5) | (16u - (uint32_t)(l)))
    uint32_t m0 = umax2(umax2(KEY(c0,0,0),  KEY(c0,8,1)),  umax2(KEY(c0,16,2),  KEY(c0,24,3)));
    uint32_t m1 = umax2(umax2(KEY(c1,0,4),  KEY(c1,8,5)),  umax2(KEY(c1,16,6),  KEY(c1,24,7)));
    uint32_t m2 = umax2(umax2(KEY(c2,0,8),  KEY(c2,8,9)),  umax2(KEY(c2,16,10), KEY(c2,24,11)));
    uint32_t m3 = umax2(umax2(KEY(c3,0,12), KEY(c3,8,13)), umax2(KEY(c3,16,14), KEY(c3,24,15)));
    uint32_t m  = umax2(umax2(umax2(m0, m1), umax2(m2, m3)), KEY(c4,0,16));
#undef KEY
    uint32_t lvl = 16u - (m & 31u);
    packed |= ((uint64_t)lvl) << (8 * s);
    if (s < 7){
      #pragma unroll
      for (int r = 0; r < 11; ++r){
        uint32_t qo = base[r * 528 + s];      HDEC(qo);
        uint32_t qn = base[r * 528 + s + 11]; HINC(qn);
      }
    }
  }
#undef HINC
#undef HDEC
  *(uint64_t*)(xm + img * HW + (h0 + r4) * 512 + w0) = packed;
}

// ---------------------------------------------------------------------------
// block reduction of per-thread su[16]/sq[16] -> partials[block][32]
// ---------------------------------------------------------------------------
__device__ __forceinline__ void reduce16(float* su, float* sq, float* __restrict__ partials){
  __shared__ float lsum[32];
  int tid = threadIdx.x;
  if (tid < 32) lsum[tid] = 0.0f;
  __syncthreads();
  #pragma unroll
  for (int o = 0; o < 16; ++o){
    float s = su[o], q = sq[o];
    #pragma unroll
    for (int off = 32; off >= 1; off >>= 1){
      s += __shfl_xor(s, off);
      q += __shfl_xor(q, off);
    }
    if ((tid & 63) == 0){ atomicAdd(&lsum[o], s); atomicAdd(&lsum[16 + o], q); }
  }
  __syncthreads();
  if (tid < 32) partials[blockIdx.x * 32 + tid] = lsum[tid];
}

// ---------------------------------------------------------------------------
// K1: stats of p1 = conv1x1(xm). 4 px/thread. grid 512 x 256.
// ---------------------------------------------------------------------------
__global__ __launch_bounds__(256) void k_stats1(const uint8_t* __restrict__ xm,
                                                const float* __restrict__ w1,
                                                const float* __restrict__ b1,
                                                float* __restrict__ partials){
  int t0 = (blockIdx.x * 256 + threadIdx.x) << 2;
  int b = t0 >> 18, hw = t0 & (HW - 1);
  uint32_t q0 = *(const uint32_t*)(xm + (b * 3 + 0) * HW + hw);
  uint32_t q1 = *(const uint32_t*)(xm + (b * 3 + 1) * HW + hw);
  uint32_t q2 = *(const uint32_t*)(xm + (b * 3 + 2) * HW + hw);
  float su[16], sq[16];
  #pragma unroll
  for (int o = 0; o < 16; ++o){ su[o] = 0.0f; sq[o] = 0.0f; }
  #pragma unroll
  for (int px = 0; px < 4; ++px){
    float x0 = (float)((q0 >> (8 * px)) & 0xffu) * 0.0625f;
    float x1 = (float)((q1 >> (8 * px)) & 0xffu) * 0.0625f;
    float x2 = (float)((q2 >> (8 * px)) & 0xffu) * 0.0625f;
    #pragma unroll
    for (int o = 0; o < 16; ++o){
      float v = b1[o] + w1[o*3]*x0 + w1[o*3+1]*x1 + w1[o*3+2]*x2;
      su[o] += v; sq[o] += v * v;
    }
  }
  reduce16(su, sq, partials);
}

// ---------------------------------------------------------------------------
// K2: recompute p1, bn1+lrelu, p2 = conv1x1, stats of p2. 4 px/thread.
// ---------------------------------------------------------------------------
__global__ __launch_bounds__(256) void k_stats2(const uint8_t* __restrict__ xm,
                                                const float* __restrict__ w1,
                                                const float* __restrict__ b1,
                                                const float* __restrict__ w2,
                                                const float* __restrict__ b2,
                                                const float* __restrict__ params,
                                                float* __restrict__ partials){
  int t0 = (blockIdx.x * 256 + threadIdx.x) << 2;
  int b = t0 >> 18, hw = t0 & (HW - 1);
  uint32_t q0 = *(const uint32_t*)(xm + (b * 3 + 0) * HW + hw);
  uint32_t q1 = *(const uint32_t*)(xm + (b * 3 + 1) * HW + hw);
  uint32_t q2 = *(const uint32_t*)(xm + (b * 3 + 2) * HW + hw);
  float tv[4][16];
  #pragma unroll
  for (int px = 0; px < 4; ++px){
    float x0 = (float)((q0 >> (8 * px)) & 0xffu) * 0.0625f;
    float x1 = (float)((q1 >> (8 * px)) & 0xffu) * 0.0625f;
    float x2 = (float)((q2 >> (8 * px)) & 0xffu) * 0.0625f;
    #pragma unroll
    for (int o = 0; o < 16; ++o){
      float v = b1[o] + w1[o*3]*x0 + w1[o*3+1]*x1 + w1[o*3+2]*x2;
      tv[px][o] = lrelu(v * params[o] + params[16 + o]);
    }
  }
  float su[16], sq[16];
  #pragma unroll
  for (int o = 0; o < 16; ++o){ su[o] = 0.0f; sq[o] = 0.0f; }
  #pragma unroll
  for (int o = 0; o < 16; ++o){
    #pragma unroll
    for (int px = 0; px < 4; ++px){
      float acc = b2[o];
      #pragma unroll
      for (int c = 0; c < 16; ++c) acc = fmaf(w2[o*16 + c], tv[px][c], acc);
      su[o] += acc; sq[o] += acc * acc;
    }
  }
  reduce16(su, sq, partials);
}

// ---------------------------------------------------------------------------
// K3: recompute p2, bn2+lrelu, write p (bf16). 4 px/thread.
// ---------------------------------------------------------------------------
__global__ __launch_bounds__(256) void k_prep(const uint8_t* __restrict__ xm,
                                              const float* __restrict__ w1,
                                              const float* __restrict__ b1,
                                              const float* __restrict__ w2,
                                              const float* __restrict__ b2,
                                              const float* __restrict__ params,
                                              bf16* __restrict__ p){
  int t0 = (blockIdx.x * 256 + threadIdx.x) << 2;
  int b = t0 >> 18, hw = t0 & (HW - 1);
  uint32_t q0 = *(const uint32_t*)(xm + (b * 3 + 0) * HW + hw);
  uint32_t q1 = *(const uint32_t*)(xm + (b * 3 + 1) * HW + hw);
  uint32_t q2 = *(const uint32_t*)(xm + (b * 3 + 2) * HW + hw);
  float tv[4][16];
  #pragma unroll
  for (int px = 0; px < 4; ++px){
    float x0 = (float)((q0 >> (8 * px)) & 0xffu) * 0.0625f;
    float x1 = (float)((q1 >> (8 * px)) & 0xffu) * 0.0625f;
    float x2 = (float)((q2 >> (8 * px)) & 0xffu) * 0.0625f;
    #pragma unroll
    for (int o = 0; o < 16; ++o){
      float v = b1[o] + w1[o*3]*x0 + w1[o*3+1]*x1 + w1[o*3+2]*x2;
      tv[px][o] = lrelu(v * params[o] + params[16 + o]);
    }
  }
  #pragma unroll
  for (int o = 0; o < 16; ++o){
    uint32_t w01 = 0, w23 = 0;
    #pragma unroll
    for (int px = 0; px < 4; ++px){
      float acc = b2[o];
      #pragma unroll
      for (int c = 0; c < 16; ++c) acc = fmaf(w2[o*16 + c], tv[px][c], acc);
      float v = lrelu(acc * params[32 + o] + params[48 + o]);
      uint32_t bits = (uint32_t)f2bu(v);
      if (px == 0) w01 = bits;
      else if (px == 1) w01 |= bits << 16;
      else if (px == 2) w23 = bits;
      else w23 |= bits << 16;
    }
    uint2 ov; ov.x = w01; ov.y = w23;
    *(uint2*)((ushort*)p + (b * 16 + o) * HW + hw) = ov;
  }
}

// ---------------------------------------------------------------------------
// row loader for depthwise conv: 10 values (cols w0-1 .. w0+8), zero-padded
// ---------------------------------------------------------------------------
__device__ __forceinline__ void load_row10(const ushort* __restrict__ rp, int w0, float* v){
  uint4 cc = *(const uint4*)(rp + w0);                     // 16B aligned
  uint32_t l = (w0 == 0)   ? 0u : (uint32_t)rp[w0 - 1];
  uint32_t r = (w0 == 504) ? 0u : (uint32_t)rp[w0 + 8];
  v[0] = us2f(l);
  v[1] = us2f(cc.x & 0xffffu); v[2] = us2f(cc.x >> 16);
  v[3] = us2f(cc.y & 0xffffu); v[4] = us2f(cc.y >> 16);
  v[5] = us2f(cc.z & 0xffffu); v[6] = us2f(cc.z >> 16);
  v[7] = us2f(cc.w & 0xffffu); v[8] = us2f(cc.w >> 16);
  v[9] = us2f(r);
}

__device__ __forceinline__ void zero_row10(float* v){
  #pragma unroll
  for (int j = 0; j < 10; ++j) v[j] = 0.0f;
}

__device__ __forceinline__ void reduce2(float s, float q, float* __restrict__ partials){
  __shared__ float l2[2];
  int tid = threadIdx.x;
  if (tid < 2) l2[tid] = 0.0f;
  __syncthreads();
  #pragma unroll
  for (int off = 32; off >= 1; off >>= 1){
    s += __shfl_xor(s, off);
    q += __shfl_xor(q, off);
  }
  if ((tid & 63) == 0){ atomicAdd(&l2[0], s); atomicAdd(&l2[1], q); }
  __syncthreads();
  if (tid < 2) partials[blockIdx.x * 2 + tid] = l2[tid];
}

// ---------------------------------------------------------------------------
// A: conv stats only. 8 px/thread. block = (plane, 4-row group). grid 4096.
// ---------------------------------------------------------------------------
__global__ __launch_bounds__(256) void k_convstat(const bf16* __restrict__ d,
                                                  const float* __restrict__ dw,
                                                  float* __restrict__ P1){
  int bid = blockIdx.x;
  int plane = bid >> 7, rg = bid & 127;
  int f = plane & 15;
  int tid = threadIdx.x;
  int h  = (rg << 2) + (tid >> 6);
  int w0 = (tid & 63) << 3;
  const ushort* pl = (const ushort*)d + plane * HW;
  float wf[9];
  #pragma unroll
  for (int i = 0; i < 9; ++i) wf[i] = dw[f * 9 + i];
  float v[3][10];
  #pragma unroll
  for (int dy = 0; dy < 3; ++dy){
    int row = h + dy - 1;
    if ((unsigned)row < 512u) load_row10(pl + row * 512, w0, v[dy]);
    else zero_row10(v[dy]);
  }
  float s = 0.0f, q = 0.0f;
  #pragma unroll
  for (int k = 0; k < 8; ++k){
    float acc = 0.0f;
    #pragma unroll
    for (int dy = 0; dy < 3; ++dy)
      #pragma unroll
      for (int dx = 0; dx < 3; ++dx)
        acc = fmaf(wf[dy*3 + dx], v[dy][k + dx], acc);
    s += acc; q += acc * acc;
  }
  reduce2(s, q, P1);
}

// ---------------------------------------------------------------------------
// B: recompute conv, bnC+lrelu, write d_t (bf16), stats of d_t. 8 px/thread.
// ---------------------------------------------------------------------------
__global__ __launch_bounds__(256) void k_bnwrite(const bf16* __restrict__ din,
                                                 const float* __restrict__ dw,
                                                 const float* __restrict__ params,
                                                 bf16* __restrict__ dout,
                                                 float* __restrict__ P2){
  int bid = blockIdx.x;
  int plane = bid >> 7, rg = bid & 127;
  int f = plane & 15;
  int tid = threadIdx.x;
  int h  = (rg << 2) + (tid >> 6);
  int w0 = (tid & 63) << 3;
  const ushort* pl = (const ushort*)din + plane * HW;
  float wf[9];
  #pragma unroll
  for (int i = 0; i < 9; ++i) wf[i] = dw[f * 9 + i];
  float sc = params[64 + f], sh = params[80 + f];
  float v[3][10];
  #pragma unroll
  for (int dy = 0; dy < 3; ++dy){
    int row = h + dy - 1;
    if ((unsigned)row < 512u) load_row10(pl + row * 512, w0, v[dy]);
    else zero_row10(v[dy]);
  }
  float s = 0.0f, q = 0.0f;
  uint32_t ob[4];
  #pragma unroll
  for (int k = 0; k < 8; ++k){
    float acc = 0.0f;
    #pragma unroll
    for (int dy = 0; dy < 3; ++dy)
      #pragma unroll
      for (int dx = 0; dx < 3; ++dx)
        acc = fmaf(wf[dy*3 + dx], v[dy][k + dx], acc);
    float vv = lrelu(acc * sc + sh);
    uint32_t bits = (uint32_t)f2bu(vv);
    if ((k & 1) == 0) ob[k >> 1] = bits; else ob[k >> 1] |= bits << 16;
    s += vv; q += vv * vv;
  }
  uint4 ov; ov.x = ob[0]; ov.y = ob[1]; ov.z = ob[2]; ov.w = ob[3];
  *(uint4*)((ushort*)dout + plane * HW + h * 512 + w0) = ov;
  reduce2(s, q, P2);
}

// ---------------------------------------------------------------------------
// finalize: prepare-stage BN (512-block x 32 partials layout)
// ---------------------------------------------------------------------------
__global__ __launch_bounds__(256) void k_fin_prep(const float* __restrict__ partials,
                                                  const float* __restrict__ g,
                                                  const float* __restrict__ bb,
                                                  float* __restrict__ params,
                                                  int offS, int offT){
  int tid = threadIdx.x;
  int o = tid & 15, c = tid >> 4;
  double S = 0.0, Q = 0.0;
  for (int i = c * 32; i < (c + 1) * 32; ++i){
    S += (double)partials[i * 32 + o];
    Q += (double)partials[i * 32 + 16 + o];
  }
  __shared__ double lS[256], lQ[256];
  lS[tid] = S; lQ[tid] = Q; __syncthreads();
  for (int st = 8; st >= 1; st >>= 1){
    if (c < st){ lS[tid] += lS[tid + st * 16]; lQ[tid] += lQ[tid + st * 16]; }
    __syncthreads();
  }
  if (tid < 16){
    double m = lS[tid] / 524288.0;
    double v = lQ[tid] / 524288.0 - m * m;
    float sc = g[tid] / sqrtf((float)v + EPSF);
    params[offS + tid] = sc;
    params[offT + tid] = bb[tid] - (float)m * sc;
  }
}

// gather for 4096-block x 2 partials layout: channel o -> 256 entries
__device__ __forceinline__ void gather256(const float* __restrict__ P, int o, int c,
                                          double& S, double& Q){
  #pragma unroll
  for (int i = 0; i < 16; ++i){
    int li = c * 16 + i;
    int b = li >> 7, rg = li & 127;
    int blk = ((b * 16 + o) << 7) + rg;
    S += (double)P[blk * 2];
    Q += (double)P[blk * 2 + 1];
  }
}

__device__ __forceinline__ void tree16(double* lS, double* lQ, int tid, int c){
  __syncthreads();
  for (int st = 8; st >= 1; st >>= 1){
    if (c < st){ lS[tid] += lS[tid + st * 16]; lQ[tid] += lQ[tid + st * 16]; }
    __syncthreads();
  }
}

// ---------------------------------------------------------------------------
// merged loop finalize: bnA (conv BN params) from P1; dA (wdt/hgt affine
// params for iteration tdA) from P2.
// ---------------------------------------------------------------------------
__global__ __launch_bounds__(256) void k_finloop(const float* __restrict__ P1,
                                                 const float* __restrict__ P2,
                                                 const float* __restrict__ gd,
                                                 const float* __restrict__ bd,
                                                 const float* __restrict__ ww,
                                                 const float* __restrict__ gw,
                                                 const float* __restrict__ bw,
                                                 const float* __restrict__ wh,
                                                 const float* __restrict__ gh,
                                                 const float* __restrict__ bh,
                                                 float* __restrict__ params,
                                                 int tdA, int do_bnA){
  __shared__ double lS[256], lQ[256];
  int tid = threadIdx.x;
  int o = tid & 15, c = tid >> 4;
  if (do_bnA){
    double S = 0.0, Q = 0.0;
    gather256(P1, o, c, S, Q);
    lS[tid] = S; lQ[tid] = Q;
    tree16(lS, lQ, tid, c);
    if (tid < 16){
      double m = lS[tid] / 524288.0;
      double v = lQ[tid] / 524288.0 - m * m;
      float sc = gd[tid] / sqrtf((float)v + EPSF);
      params[64 + tid] = sc;
      params[80 + tid] = bd[tid] - (float)m * sc;
    }
    __syncthreads();
  }
  if (tdA >= 0){
    double S = 0.0, Q = 0.0;
    gather256(P2, o, c, S, Q);
    lS[tid] = S; lQ[tid] = Q;
    tree16(lS, lQ, tid, c);
    if (tid < 16){
      float m = (float)(lS[tid] / 524288.0);
      float v = (float)(lQ[tid] / 524288.0) - m * m;
      float sw = ww[tid] * gw[tid] / sqrtf(ww[tid] * ww[tid] * v + EPSF);
      float tw = bw[tid] - m * sw;
      float s2 = wh[tid] * gh[tid] / sqrtf(wh[tid] * wh[tid] * v + EPSF);
      float t2 = bh[tid] - m * s2;
      int base = 96 + tdA * 64;
      params[base + tid]      = sw;
      params[base + 16 + tid] = tw;
      params[base + 32 + tid] = s2;
      params[base + 48 + tid] = t2;
    }
  }
}

// ---------------------------------------------------------------------------
// F: assemble out. 8 px/thread, all loads uint4, stores float4. grid 2048.
// ---------------------------------------------------------------------------
__device__ __forceinline__ void load8(const ushort* __restrict__ ptr, float* v){
  uint4 cc = *(const uint4*)ptr;
  v[0] = us2f(cc.x & 0xffffu); v[1] = us2f(cc.x >> 16);
  v[2] = us2f(cc.y & 0xffffu); v[3] = us2f(cc.y >> 16);
  v[4] = us2f(cc.z & 0xffffu); v[5] = us2f(cc.z >> 16);
  v[6] = us2f(cc.w & 0xffffu); v[7] = us2f(cc.w >> 16);
}

__global__ __launch_bounds__(256) void k_final(const bf16* __restrict__ p,
                                               const bf16* __restrict__ d1,
                                               const bf16* __restrict__ d2,
                                               const bf16* __restrict__ d3,
                                               const bf16* __restrict__ d4,
                                               const bf16* __restrict__ d5,
                                               const float* __restrict__ params,
                                               float* __restrict__ out){
  int gid = blockIdx.x * 256 + threadIdx.x;     // 0 .. 524287
  int f = gid >> 15;
  int hw = (gid & 32767) << 3;
  int fo = f * HW + hw;
  int f1 = (16 + f) * HW + hw;
  float pf[8], pg[8];
  load8((const ushort*)p + fo, pf);
  load8((const ushort*)p + f1, pg);
  float a00[8], a01[8], a10[8], a11[8];
  #pragma unroll
  for (int k = 0; k < 8; ++k){ a00[k] = pf[k]; a01[k] = pg[k]; a10[k] = pf[k]; a11[k] = pg[k]; }
  const bf16* dptrs[5] = {d1, d2, d3, d4, d5};
  #pragma unroll
  for (int t = 0; t < 5; ++t){
    const ushort* dp = (const ushort*)dptrs[t];
    float dv0[8], dv1[8];
    load8(dp + fo, dv0);
    load8(dp + f1, dv1);
    float sw = params[96 + t*64 + f],      tw = params[96 + t*64 + 16 + f];
    float sh = params[96 + t*64 + 32 + f], th = params[96 + t*64 + 48 + f];
    #pragma unroll
    for (int k = 0; k < 8; ++k){
      a00[k] += lrelu(fmaf(dv0[k], sw, tw));
      a01[k] += lrelu(fmaf(dv0[k], sh, th));
      a10[k] += lrelu(fmaf(dv1[k], sw, tw));
      a11[k] += lrelu(fmaf(dv1[k], sh, th));
    }
  }
  #pragma unroll
  for (int half = 0; half < 2; ++half){
    float4 v0 = { a00[half*4+0], a00[half*4+1], a00[half*4+2], a00[half*4+3] };
    float4 v1 = { a01[half*4+0], a01[half*4+1], a01[half*4+2], a01[half*4+3] };
    float4 v2 = { a10[half*4+0], a10[half*4+1], a10[half*4+2], a10[half*4+3] };
    float4 v3 = { a11[half*4+0], a11[half*4+1], a11[half*4+2], a11[half*4+3] };
    *(float4*)(out + f * HW + hw + half*4)        = v0;
    *(float4*)(out + (16 + f) * HW + hw + half*4) = v1;
    *(float4*)(out + (32 + f) * HW + hw + half*4) = v2;
    *(float4*)(out + (48 + f) * HW + hw + half*4) = v3;
  }
}

// ---------------------------------------------------------------------------
extern "C" void kernel_launch(void* const* d_in, const int* in_sizes, int n_in,
                              void* d_out, int out_size, void* d_ws, size_t ws_size,
                              hipStream_t stream){
  (void)in_sizes; (void)n_in; (void)out_size;
  const float* x   = (const float*)d_in[0];
  const float* w1  = (const float*)d_in[1];
  const float* b1  = (const float*)d_in[2];
  const float* g1  = (const float*)d_in[3];
  const float* be1 = (const float*)d_in[4];
  const float* w2  = (const float*)d_in[5];
  const float* b2  = (const float*)d_in[6];
  const float* g2  = (const float*)d_in[7];
  const float* be2 = (const float*)d_in[8];
  const float* dw  = (const float*)d_in[9];
  const float* gd  = (const float*)d_in[10];
  const float* bd  = (const float*)d_in[11];
  const float* ww  = (const float*)d_in[12];
  const float* gw  = (const float*)d_in[13];
  const float* bw  = (const float*)d_in[14];
  const float* wh  = (const float*)d_in[15];
  const float* gh  = (const float*)d_in[16];
  const float* bh  = (const float*)d_in[17];
  float* out = (float*)d_out;

  char* ws = (char*)d_ws;
  size_t off = 0;
  auto alloc = [&](size_t sz) -> void* {
    void* ptr = ws + off;
    off = (off + sz + 4095) & ~(size_t)4095;
    return ptr;
  };
  uint8_t* qpad  = (uint8_t*)alloc((size_t)6 * 522 * 528);
  uint8_t* xm    = (uint8_t*)alloc((size_t)6 * HW);
  bf16*    p     = (bf16*)   alloc((size_t)32 * HW * 2);
  bf16*    dbuf[5];
  for (int i = 0; i < 5; ++i) dbuf[i] = (bf16*)alloc((size_t)32 * HW * 2);
  float*   Pp     = (float*)  alloc((size_t)512 * 32 * 4);
  float*   P1     = (float*)  alloc((size_t)4096 * 2 * 4);
  float*   P2     = (float*)  alloc((size_t)4096 * 2 * 4);
  float*   params = (float*)  alloc(4096);
  if (ws_size < off) return;   // workspace too small: fail visibly (untouched out)

  k_quant_pad<<<dim3((6*522*522 + 255)/256), dim3(256), 0, stream>>>(x, qpad);
  k_mode     <<<dim3(768), dim3(256), 0, stream>>>(qpad, xm);
  k_stats1   <<<dim3(512), dim3(256), 0, stream>>>(xm, w1, b1, Pp);
  k_fin_prep <<<dim3(1),   dim3(256), 0, stream>>>(Pp, g1, be1, params, 0, 16);
  k_stats2   <<<dim3(512), dim3(256), 0, stream>>>(xm, w1, b1, w2, b2, params, Pp);
  k_fin_prep <<<dim3(1),   dim3(256), 0, stream>>>(Pp, g2, be2, params, 32, 48);
  k_prep     <<<dim3(512), dim3(256), 0, stream>>>(xm, w1, b1, w2, b2, params, p);

  const bf16* dcur = p;
  for (int t = 0; t < 5; ++t){
    k_convstat<<<dim3(4096), dim3(256), 0, stream>>>(dcur, dw, P1);
    k_finloop <<<dim3(1),    dim3(256), 0, stream>>>(P1, P2, gd, bd, ww, gw, bw,
                                                     wh, gh, bh, params, t - 1, 1);
    k_bnwrite <<<dim3(4096), dim3(256), 0, stream>>>(dcur, dw, params, dbuf[t], P2);
    dcur = dbuf[t];
  }
  k_finloop<<<dim3(1), dim3(256), 0, stream>>>(P1, P2, gd, bd, ww, gw, bw,
                                               wh, gh, bh, params, 4, 0);
  k_final<<<dim3(2048), dim3(256), 0, stream>>>(p, dbuf[0], dbuf[1], dbuf[2],
                                                dbuf[3], dbuf[4], params, out);
}

// Round 5
// 277.358 us; speedup vs baseline: 2.9320x; 1.3234x over previous
//
#include <hip/hip_runtime.h>
#include <hip/hip_bf16.h>
#include <stdint.h>
#include <stddef.h>

#define HW 262144          // 512*512
#define EPSF 1e-5f

typedef __hip_bfloat16 bf16;

__device__ __forceinline__ float us2f(uint32_t u){
  union { uint32_t i; float f; } c; c.i = u << 16; return c.f;
}
__device__ __forceinline__ ushort f2bu(float v){
  union { bf16 h; ushort u; } c; c.h = __float2bfloat16(v); return c.u;
}
__device__ __forceinline__ float lrelu(float v){ return v > 0.0f ? v : 0.01f * v; }
__device__ __forceinline__ uint32_t umax2(uint32_t a, uint32_t b){ return a > b ? a : b; }

// ---------------------------------------------------------------------------
// K0a: quantize x to level k = rint(x*255/16), materialize reflect-padded u8
// plane [6][522 rows][pitch 528]
// ---------------------------------------------------------------------------
__global__ __launch_bounds__(256) void k_quant_pad(const float* __restrict__ x,
                                                   uint8_t* __restrict__ qpad){
  int idx = blockIdx.x * 256 + threadIdx.x;
  if (idx >= 6 * 522 * 522) return;
  int pw = idx % 522; int t = idx / 522; int ph = t % 522; int img = t / 522;
  int h = ph - 5; h = h < 0 ? -h : h; if (h > 511) h = 1022 - h;
  int w = pw - 5; w = w < 0 ? -w : w; if (w > 511) w = 1022 - w;
  float v = x[img * HW + h * 512 + w];
  int k = (int)rintf((v * 255.0f) / 16.0f);   // round-half-even, matches jnp.round
  qpad[img * (522 * 528) + ph * 528 + pw] = (uint8_t)k;
}

// ---------------------------------------------------------------------------
// K0b: 11x11 mode filter. Block = 4 output rows x 64 threads x 8 px.
// Tile (14 rows x 528 B) staged in LDS; per-thread sliding 17-bin histogram
// packed 8-bit into 5 u32 registers. ALL loops over LDS bytes kept ROLLED
// (#pragma unroll 1) so the compiler cannot hoist the ~275 ds_read_u8 into
// one giant live range (that hoisting caused a 256-VGPR spill, r3/r4).
// Argmax via packed keys (cnt<<5)|(16-lvl) + max tree (tie -> smallest lvl).
// ---------------------------------------------------------------------------
__global__ __launch_bounds__(256) void k_mode(const uint8_t* __restrict__ qpad,
                                              uint8_t* __restrict__ xm){
  __shared__ uint8_t tile[14 * 528];          // 7392 B
  int tid = threadIdx.x;
  int img = blockIdx.x >> 7;
  int h0  = (blockIdx.x & 127) << 2;          // first output row of block
  {
    const uint4* g4 = (const uint4*)(qpad + img * (522 * 528) + h0 * 528);
    uint4* t4 = (uint4*)tile;
    t4[tid] = g4[tid];                        // 0..255
    if (tid < 206) t4[tid + 256] = g4[tid + 256];   // 256..461 (462 total)
  }
  __syncthreads();
  int r4 = tid >> 6;                          // row within block 0..3
  int w0 = (tid & 63) << 3;                   // 0..504
  const uint8_t* base = tile + r4 * 528 + w0;
  uint32_t c0 = 0, c1 = 0, c2 = 0, c3 = 0, c4 = 0;
#define HINC(q) { uint32_t inc_ = 1u << (((q) & 3u) << 3); uint32_t rr_ = (q) >> 2; \
    c0 += (rr_==0u)?inc_:0u; c1 += (rr_==1u)?inc_:0u; c2 += (rr_==2u)?inc_:0u; \
    c3 += (rr_==3u)?inc_:0u; c4 += (rr_==4u)?inc_:0u; }
#define HDEC(q) { uint32_t inc_ = 1u << (((q) & 3u) << 3); uint32_t rr_ = (q) >> 2; \
    c0 -= (rr_==0u)?inc_:0u; c1 -= (rr_==1u)?inc_:0u; c2 -= (rr_==2u)?inc_:0u; \
    c3 -= (rr_==3u)?inc_:0u; c4 -= (rr_==4u)?inc_:0u; }
  #pragma unroll 1
  for (int r = 0; r < 11; ++r){
    const uint8_t* row = base + r * 528;
    #pragma unroll
    for (int j = 0; j < 11; ++j){ uint32_t q = row[j]; HINC(q); }
  }
  uint64_t packed = 0;
  #pragma unroll 1
  for (int s = 0; s < 8; ++s){
    // key(l) = (cnt<<5) | (16-l); max key -> max cnt, tie -> smallest level
#define KEY(reg, sh, l) (((((reg) >> (sh)) & 0xffu) << 5) | (16u - (uint32_t)(l)))
    uint32_t m0 = umax2(umax2(KEY(c0,0,0),  KEY(c0,8,1)),  umax2(KEY(c0,16,2),  KEY(c0,24,3)));
    uint32_t m1 = umax2(umax2(KEY(c1,0,4),  KEY(c1,8,5)),  umax2(KEY(c1,16,6),  KEY(c1,24,7)));
    uint32_t m2 = umax2(umax2(KEY(c2,0,8),  KEY(c2,8,9)),  umax2(KEY(c2,16,10), KEY(c2,24,11)));
    uint32_t m3 = umax2(umax2(KEY(c3,0,12), KEY(c3,8,13)), umax2(KEY(c3,16,14), KEY(c3,24,15)));
    uint32_t m  = umax2(umax2(umax2(m0, m1), umax2(m2, m3)), KEY(c4,0,16));
#undef KEY
    uint32_t lvl = 16u - (m & 31u);
    packed |= ((uint64_t)lvl) << (8 * s);
    if (s < 7){
      #pragma unroll
      for (int r = 0; r < 11; ++r){
        uint32_t qo = base[r * 528 + s];      HDEC(qo);
        uint32_t qn = base[r * 528 + s + 11]; HINC(qn);
      }
    }
  }
#undef HINC
#undef HDEC
  *(uint64_t*)(xm + img * HW + (h0 + r4) * 512 + w0) = packed;
}

// ---------------------------------------------------------------------------
// block reduction of per-thread su[16]/sq[16] -> partials[block][32]
// ---------------------------------------------------------------------------
__device__ __forceinline__ void reduce16(float* su, float* sq, float* __restrict__ partials){
  __shared__ float lsum[32];
  int tid = threadIdx.x;
  if (tid < 32) lsum[tid] = 0.0f;
  __syncthreads();
  #pragma unroll
  for (int o = 0; o < 16; ++o){
    float s = su[o], q = sq[o];
    #pragma unroll
    for (int off = 32; off >= 1; off >>= 1){
      s += __shfl_xor(s, off);
      q += __shfl_xor(q, off);
    }
    if ((tid & 63) == 0){ atomicAdd(&lsum[o], s); atomicAdd(&lsum[16 + o], q); }
  }
  __syncthreads();
  if (tid < 32) partials[blockIdx.x * 32 + tid] = lsum[tid];
}

// ---------------------------------------------------------------------------
// K1: stats of p1 = conv1x1(xm). 4 px/thread. grid 512 x 256.
// ---------------------------------------------------------------------------
__global__ __launch_bounds__(256) void k_stats1(const uint8_t* __restrict__ xm,
                                                const float* __restrict__ w1,
                                                const float* __restrict__ b1,
                                                float* __restrict__ partials){
  int t0 = (blockIdx.x * 256 + threadIdx.x) << 2;
  int b = t0 >> 18, hw = t0 & (HW - 1);
  uint32_t q0 = *(const uint32_t*)(xm + (b * 3 + 0) * HW + hw);
  uint32_t q1 = *(const uint32_t*)(xm + (b * 3 + 1) * HW + hw);
  uint32_t q2 = *(const uint32_t*)(xm + (b * 3 + 2) * HW + hw);
  float su[16], sq[16];
  #pragma unroll
  for (int o = 0; o < 16; ++o){ su[o] = 0.0f; sq[o] = 0.0f; }
  #pragma unroll
  for (int px = 0; px < 4; ++px){
    float x0 = (float)((q0 >> (8 * px)) & 0xffu) * 0.0625f;
    float x1 = (float)((q1 >> (8 * px)) & 0xffu) * 0.0625f;
    float x2 = (float)((q2 >> (8 * px)) & 0xffu) * 0.0625f;
    #pragma unroll
    for (int o = 0; o < 16; ++o){
      float v = b1[o] + w1[o*3]*x0 + w1[o*3+1]*x1 + w1[o*3+2]*x2;
      su[o] += v; sq[o] += v * v;
    }
  }
  reduce16(su, sq, partials);
}

// ---------------------------------------------------------------------------
// K2: recompute p1, bn1+lrelu, p2 = conv1x1, stats of p2. 4 px/thread.
// ---------------------------------------------------------------------------
__global__ __launch_bounds__(256) void k_stats2(const uint8_t* __restrict__ xm,
                                                const float* __restrict__ w1,
                                                const float* __restrict__ b1,
                                                const float* __restrict__ w2,
                                                const float* __restrict__ b2,
                                                const float* __restrict__ params,
                                                float* __restrict__ partials){
  int t0 = (blockIdx.x * 256 + threadIdx.x) << 2;
  int b = t0 >> 18, hw = t0 & (HW - 1);
  uint32_t q0 = *(const uint32_t*)(xm + (b * 3 + 0) * HW + hw);
  uint32_t q1 = *(const uint32_t*)(xm + (b * 3 + 1) * HW + hw);
  uint32_t q2 = *(const uint32_t*)(xm + (b * 3 + 2) * HW + hw);
  float tv[4][16];
  #pragma unroll
  for (int px = 0; px < 4; ++px){
    float x0 = (float)((q0 >> (8 * px)) & 0xffu) * 0.0625f;
    float x1 = (float)((q1 >> (8 * px)) & 0xffu) * 0.0625f;
    float x2 = (float)((q2 >> (8 * px)) & 0xffu) * 0.0625f;
    #pragma unroll
    for (int o = 0; o < 16; ++o){
      float v = b1[o] + w1[o*3]*x0 + w1[o*3+1]*x1 + w1[o*3+2]*x2;
      tv[px][o] = lrelu(v * params[o] + params[16 + o]);
    }
  }
  float su[16], sq[16];
  #pragma unroll
  for (int o = 0; o < 16; ++o){ su[o] = 0.0f; sq[o] = 0.0f; }
  #pragma unroll
  for (int o = 0; o < 16; ++o){
    #pragma unroll
    for (int px = 0; px < 4; ++px){
      float acc = b2[o];
      #pragma unroll
      for (int c = 0; c < 16; ++c) acc = fmaf(w2[o*16 + c], tv[px][c], acc);
      su[o] += acc; sq[o] += acc * acc;
    }
  }
  reduce16(su, sq, partials);
}

// ---------------------------------------------------------------------------
// K3: recompute p2, bn2+lrelu, write p (bf16). 4 px/thread.
// ---------------------------------------------------------------------------
__global__ __launch_bounds__(256) void k_prep(const uint8_t* __restrict__ xm,
                                              const float* __restrict__ w1,
                                              const float* __restrict__ b1,
                                              const float* __restrict__ w2,
                                              const float* __restrict__ b2,
                                              const float* __restrict__ params,
                                              bf16* __restrict__ p){
  int t0 = (blockIdx.x * 256 + threadIdx.x) << 2;
  int b = t0 >> 18, hw = t0 & (HW - 1);
  uint32_t q0 = *(const uint32_t*)(xm + (b * 3 + 0) * HW + hw);
  uint32_t q1 = *(const uint32_t*)(xm + (b * 3 + 1) * HW + hw);
  uint32_t q2 = *(const uint32_t*)(xm + (b * 3 + 2) * HW + hw);
  float tv[4][16];
  #pragma unroll
  for (int px = 0; px < 4; ++px){
    float x0 = (float)((q0 >> (8 * px)) & 0xffu) * 0.0625f;
    float x1 = (float)((q1 >> (8 * px)) & 0xffu) * 0.0625f;
    float x2 = (float)((q2 >> (8 * px)) & 0xffu) * 0.0625f;
    #pragma unroll
    for (int o = 0; o < 16; ++o){
      float v = b1[o] + w1[o*3]*x0 + w1[o*3+1]*x1 + w1[o*3+2]*x2;
      tv[px][o] = lrelu(v * params[o] + params[16 + o]);
    }
  }
  #pragma unroll
  for (int o = 0; o < 16; ++o){
    uint32_t w01 = 0, w23 = 0;
    #pragma unroll
    for (int px = 0; px < 4; ++px){
      float acc = b2[o];
      #pragma unroll
      for (int c = 0; c < 16; ++c) acc = fmaf(w2[o*16 + c], tv[px][c], acc);
      float v = lrelu(acc * params[32 + o] + params[48 + o]);
      uint32_t bits = (uint32_t)f2bu(v);
      if (px == 0) w01 = bits;
      else if (px == 1) w01 |= bits << 16;
      else if (px == 2) w23 = bits;
      else w23 |= bits << 16;
    }
    uint2 ov; ov.x = w01; ov.y = w23;
    *(uint2*)((ushort*)p + (b * 16 + o) * HW + hw) = ov;
  }
}

// ---------------------------------------------------------------------------
// row loader for depthwise conv: 10 values (cols w0-1 .. w0+8), zero-padded
// ---------------------------------------------------------------------------
__device__ __forceinline__ void load_row10(const ushort* __restrict__ rp, int w0, float* v){
  uint4 cc = *(const uint4*)(rp + w0);                     // 16B aligned
  uint32_t l = (w0 == 0)   ? 0u : (uint32_t)rp[w0 - 1];
  uint32_t r = (w0 == 504) ? 0u : (uint32_t)rp[w0 + 8];
  v[0] = us2f(l);
  v[1] = us2f(cc.x & 0xffffu); v[2] = us2f(cc.x >> 16);
  v[3] = us2f(cc.y & 0xffffu); v[4] = us2f(cc.y >> 16);
  v[5] = us2f(cc.z & 0xffffu); v[6] = us2f(cc.z >> 16);
  v[7] = us2f(cc.w & 0xffffu); v[8] = us2f(cc.w >> 16);
  v[9] = us2f(r);
}

__device__ __forceinline__ void zero_row10(float* v){
  #pragma unroll
  for (int j = 0; j < 10; ++j) v[j] = 0.0f;
}

__device__ __forceinline__ void reduce2(float s, float q, float* __restrict__ partials){
  __shared__ float l2[2];
  int tid = threadIdx.x;
  if (tid < 2) l2[tid] = 0.0f;
  __syncthreads();
  #pragma unroll
  for (int off = 32; off >= 1; off >>= 1){
    s += __shfl_xor(s, off);
    q += __shfl_xor(q, off);
  }
  if ((tid & 63) == 0){ atomicAdd(&l2[0], s); atomicAdd(&l2[1], q); }
  __syncthreads();
  if (tid < 2) partials[blockIdx.x * 2 + tid] = l2[tid];
}

// ---------------------------------------------------------------------------
// A: conv stats only. 8 px/thread. block = (plane, 4-row group). grid 4096.
// ---------------------------------------------------------------------------
__global__ __launch_bounds__(256) void k_convstat(const bf16* __restrict__ d,
                                                  const float* __restrict__ dw,
                                                  float* __restrict__ P1){
  int bid = blockIdx.x;
  int plane = bid >> 7, rg = bid & 127;
  int f = plane & 15;
  int tid = threadIdx.x;
  int h  = (rg << 2) + (tid >> 6);
  int w0 = (tid & 63) << 3;
  const ushort* pl = (const ushort*)d + plane * HW;
  float wf[9];
  #pragma unroll
  for (int i = 0; i < 9; ++i) wf[i] = dw[f * 9 + i];
  float v[3][10];
  #pragma unroll
  for (int dy = 0; dy < 3; ++dy){
    int row = h + dy - 1;
    if ((unsigned)row < 512u) load_row10(pl + row * 512, w0, v[dy]);
    else zero_row10(v[dy]);
  }
  float s = 0.0f, q = 0.0f;
  #pragma unroll
  for (int k = 0; k < 8; ++k){
    float acc = 0.0f;
    #pragma unroll
    for (int dy = 0; dy < 3; ++dy)
      #pragma unroll
      for (int dx = 0; dx < 3; ++dx)
        acc = fmaf(wf[dy*3 + dx], v[dy][k + dx], acc);
    s += acc; q += acc * acc;
  }
  reduce2(s, q, P1);
}

// ---------------------------------------------------------------------------
// B: recompute conv, bnC+lrelu, write d_t (bf16), stats of d_t. 8 px/thread.
// ---------------------------------------------------------------------------
__global__ __launch_bounds__(256) void k_bnwrite(const bf16* __restrict__ din,
                                                 const float* __restrict__ dw,
                                                 const float* __restrict__ params,
                                                 bf16* __restrict__ dout,
                                                 float* __restrict__ P2){
  int bid = blockIdx.x;
  int plane = bid >> 7, rg = bid & 127;
  int f = plane & 15;
  int tid = threadIdx.x;
  int h  = (rg << 2) + (tid >> 6);
  int w0 = (tid & 63) << 3;
  const ushort* pl = (const ushort*)din + plane * HW;
  float wf[9];
  #pragma unroll
  for (int i = 0; i < 9; ++i) wf[i] = dw[f * 9 + i];
  float sc = params[64 + f], sh = params[80 + f];
  float v[3][10];
  #pragma unroll
  for (int dy = 0; dy < 3; ++dy){
    int row = h + dy - 1;
    if ((unsigned)row < 512u) load_row10(pl + row * 512, w0, v[dy]);
    else zero_row10(v[dy]);
  }
  float s = 0.0f, q = 0.0f;
  uint32_t ob[4];
  #pragma unroll
  for (int k = 0; k < 8; ++k){
    float acc = 0.0f;
    #pragma unroll
    for (int dy = 0; dy < 3; ++dy)
      #pragma unroll
      for (int dx = 0; dx < 3; ++dx)
        acc = fmaf(wf[dy*3 + dx], v[dy][k + dx], acc);
    float vv = lrelu(acc * sc + sh);
    uint32_t bits = (uint32_t)f2bu(vv);
    if ((k & 1) == 0) ob[k >> 1] = bits; else ob[k >> 1] |= bits << 16;
    s += vv; q += vv * vv;
  }
  uint4 ov; ov.x = ob[0]; ov.y = ob[1]; ov.z = ob[2]; ov.w = ob[3];
  *(uint4*)((ushort*)dout + plane * HW + h * 512 + w0) = ov;
  reduce2(s, q, P2);
}

// ---------------------------------------------------------------------------
// finalize: prepare-stage BN (512-block x 32 partials layout)
// ---------------------------------------------------------------------------
__global__ __launch_bounds__(256) void k_fin_prep(const float* __restrict__ partials,
                                                  const float* __restrict__ g,
                                                  const float* __restrict__ bb,
                                                  float* __restrict__ params,
                                                  int offS, int offT){
  int tid = threadIdx.x;
  int o = tid & 15, c = tid >> 4;
  double S = 0.0, Q = 0.0;
  for (int i = c * 32; i < (c + 1) * 32; ++i){
    S += (double)partials[i * 32 + o];
    Q += (double)partials[i * 32 + 16 + o];
  }
  __shared__ double lS[256], lQ[256];
  lS[tid] = S; lQ[tid] = Q; __syncthreads();
  for (int st = 8; st >= 1; st >>= 1){
    if (c < st){ lS[tid] += lS[tid + st * 16]; lQ[tid] += lQ[tid + st * 16]; }
    __syncthreads();
  }
  if (tid < 16){
    double m = lS[tid] / 524288.0;
    double v = lQ[tid] / 524288.0 - m * m;
    float sc = g[tid] / sqrtf((float)v + EPSF);
    params[offS + tid] = sc;
    params[offT + tid] = bb[tid] - (float)m * sc;
  }
}

// gather for 4096-block x 2 partials layout: channel o -> 256 entries
__device__ __forceinline__ void gather256(const float* __restrict__ P, int o, int c,
                                          double& S, double& Q){
  #pragma unroll
  for (int i = 0; i < 16; ++i){
    int li = c * 16 + i;
    int b = li >> 7, rg = li & 127;
    int blk = ((b * 16 + o) << 7) + rg;
    S += (double)P[blk * 2];
    Q += (double)P[blk * 2 + 1];
  }
}

__device__ __forceinline__ void tree16(double* lS, double* lQ, int tid, int c){
  __syncthreads();
  for (int st = 8; st >= 1; st >>= 1){
    if (c < st){ lS[tid] += lS[tid + st * 16]; lQ[tid] += lQ[tid + st * 16]; }
    __syncthreads();
  }
}

// ---------------------------------------------------------------------------
// merged loop finalize: bnA (conv BN params) from P1; dA (wdt/hgt affine
// params for iteration tdA) from P2.
// ---------------------------------------------------------------------------
__global__ __launch_bounds__(256) void k_finloop(const float* __restrict__ P1,
                                                 const float* __restrict__ P2,
                                                 const float* __restrict__ gd,
                                                 const float* __restrict__ bd,
                                                 const float* __restrict__ ww,
                                                 const float* __restrict__ gw,
                                                 const float* __restrict__ bw,
                                                 const float* __restrict__ wh,
                                                 const float* __restrict__ gh,
                                                 const float* __restrict__ bh,
                                                 float* __restrict__ params,
                                                 int tdA, int do_bnA){
  __shared__ double lS[256], lQ[256];
  int tid = threadIdx.x;
  int o = tid & 15, c = tid >> 4;
  if (do_bnA){
    double S = 0.0, Q = 0.0;
    gather256(P1, o, c, S, Q);
    lS[tid] = S; lQ[tid] = Q;
    tree16(lS, lQ, tid, c);
    if (tid < 16){
      double m = lS[tid] / 524288.0;
      double v = lQ[tid] / 524288.0 - m * m;
      float sc = gd[tid] / sqrtf((float)v + EPSF);
      params[64 + tid] = sc;
      params[80 + tid] = bd[tid] - (float)m * sc;
    }
    __syncthreads();
  }
  if (tdA >= 0){
    double S = 0.0, Q = 0.0;
    gather256(P2, o, c, S, Q);
    lS[tid] = S; lQ[tid] = Q;
    tree16(lS, lQ, tid, c);
    if (tid < 16){
      float m = (float)(lS[tid] / 524288.0);
      float v = (float)(lQ[tid] / 524288.0) - m * m;
      float sw = ww[tid] * gw[tid] / sqrtf(ww[tid] * ww[tid] * v + EPSF);
      float tw = bw[tid] - m * sw;
      float s2 = wh[tid] * gh[tid] / sqrtf(wh[tid] * wh[tid] * v + EPSF);
      float t2 = bh[tid] - m * s2;
      int base = 96 + tdA * 64;
      params[base + tid]      = sw;
      params[base + 16 + tid] = tw;
      params[base + 32 + tid] = s2;
      params[base + 48 + tid] = t2;
    }
  }
}

// ---------------------------------------------------------------------------
// F: assemble out. 8 px/thread, all loads uint4, stores float4. grid 2048.
// ---------------------------------------------------------------------------
__device__ __forceinline__ void load8(const ushort* __restrict__ ptr, float* v){
  uint4 cc = *(const uint4*)ptr;
  v[0] = us2f(cc.x & 0xffffu); v[1] = us2f(cc.x >> 16);
  v[2] = us2f(cc.y & 0xffffu); v[3] = us2f(cc.y >> 16);
  v[4] = us2f(cc.z & 0xffffu); v[5] = us2f(cc.z >> 16);
  v[6] = us2f(cc.w & 0xffffu); v[7] = us2f(cc.w >> 16);
}

__global__ __launch_bounds__(256) void k_final(const bf16* __restrict__ p,
                                               const bf16* __restrict__ d1,
                                               const bf16* __restrict__ d2,
                                               const bf16* __restrict__ d3,
                                               const bf16* __restrict__ d4,
                                               const bf16* __restrict__ d5,
                                               const float* __restrict__ params,
                                               float* __restrict__ out){
  int gid = blockIdx.x * 256 + threadIdx.x;     // 0 .. 524287
  int f = gid >> 15;
  int hw = (gid & 32767) << 3;
  int fo = f * HW + hw;
  int f1 = (16 + f) * HW + hw;
  float pf[8], pg[8];
  load8((const ushort*)p + fo, pf);
  load8((const ushort*)p + f1, pg);
  float a00[8], a01[8], a10[8], a11[8];
  #pragma unroll
  for (int k = 0; k < 8; ++k){ a00[k] = pf[k]; a01[k] = pg[k]; a10[k] = pf[k]; a11[k] = pg[k]; }
  const bf16* dptrs[5] = {d1, d2, d3, d4, d5};
  #pragma unroll
  for (int t = 0; t < 5; ++t){
    const ushort* dp = (const ushort*)dptrs[t];
    float dv0[8], dv1[8];
    load8(dp + fo, dv0);
    load8(dp + f1, dv1);
    float sw = params[96 + t*64 + f],      tw = params[96 + t*64 + 16 + f];
    float sh = params[96 + t*64 + 32 + f], th = params[96 + t*64 + 48 + f];
    #pragma unroll
    for (int k = 0; k < 8; ++k){
      a00[k] += lrelu(fmaf(dv0[k], sw, tw));
      a01[k] += lrelu(fmaf(dv0[k], sh, th));
      a10[k] += lrelu(fmaf(dv1[k], sw, tw));
      a11[k] += lrelu(fmaf(dv1[k], sh, th));
    }
  }
  #pragma unroll
  for (int half = 0; half < 2; ++half){
    float4 v0 = { a00[half*4+0], a00[half*4+1], a00[half*4+2], a00[half*4+3] };
    float4 v1 = { a01[half*4+0], a01[half*4+1], a01[half*4+2], a01[half*4+3] };
    float4 v2 = { a10[half*4+0], a10[half*4+1], a10[half*4+2], a10[half*4+3] };
    float4 v3 = { a11[half*4+0], a11[half*4+1], a11[half*4+2], a11[half*4+3] };
    *(float4*)(out + f * HW + hw + half*4)        = v0;
    *(float4*)(out + (16 + f) * HW + hw + half*4) = v1;
    *(float4*)(out + (32 + f) * HW + hw + half*4) = v2;
    *(float4*)(out + (48 + f) * HW + hw + half*4) = v3;
  }
}

// ---------------------------------------------------------------------------
extern "C" void kernel_launch(void* const* d_in, const int* in_sizes, int n_in,
                              void* d_out, int out_size, void* d_ws, size_t ws_size,
                              hipStream_t stream){
  (void)in_sizes; (void)n_in; (void)out_size;
  const float* x   = (const float*)d_in[0];
  const float* w1  = (const float*)d_in[1];
  const float* b1  = (const float*)d_in[2];
  const float* g1  = (const float*)d_in[3];
  const float* be1 = (const float*)d_in[4];
  const float* w2  = (const float*)d_in[5];
  const float* b2  = (const float*)d_in[6];
  const float* g2  = (const float*)d_in[7];
  const float* be2 = (const float*)d_in[8];
  const float* dw  = (const float*)d_in[9];
  const float* gd  = (const float*)d_in[10];
  const float* bd  = (const float*)d_in[11];
  const float* ww  = (const float*)d_in[12];
  const float* gw  = (const float*)d_in[13];
  const float* bw  = (const float*)d_in[14];
  const float* wh  = (const float*)d_in[15];
  const float* gh  = (const float*)d_in[16];
  const float* bh  = (const float*)d_in[17];
  float* out = (float*)d_out;

  char* ws = (char*)d_ws;
  size_t off = 0;
  auto alloc = [&](size_t sz) -> void* {
    void* ptr = ws + off;
    off = (off + sz + 4095) & ~(size_t)4095;
    return ptr;
  };
  uint8_t* qpad  = (uint8_t*)alloc((size_t)6 * 522 * 528);
  uint8_t* xm    = (uint8_t*)alloc((size_t)6 * HW);
  bf16*    p     = (bf16*)   alloc((size_t)32 * HW * 2);
  bf16*    dbuf[5];
  for (int i = 0; i < 5; ++i) dbuf[i] = (bf16*)alloc((size_t)32 * HW * 2);
  float*   Pp     = (float*)  alloc((size_t)512 * 32 * 4);
  float*   P1     = (float*)  alloc((size_t)4096 * 2 * 4);
  float*   P2     = (float*)  alloc((size_t)4096 * 2 * 4);
  float*   params = (float*)  alloc(4096);
  if (ws_size < off) return;   // workspace too small: fail visibly (untouched out)

  k_quant_pad<<<dim3((6*522*522 + 255)/256), dim3(256), 0, stream>>>(x, qpad);
  k_mode     <<<dim3(768), dim3(256), 0, stream>>>(qpad, xm);
  k_stats1   <<<dim3(512), dim3(256), 0, stream>>>(xm, w1, b1, Pp);
  k_fin_prep <<<dim3(1),   dim3(256), 0, stream>>>(Pp, g1, be1, params, 0, 16);
  k_stats2   <<<dim3(512), dim3(256), 0, stream>>>(xm, w1, b1, w2, b2, params, Pp);
  k_fin_prep <<<dim3(1),   dim3(256), 0, stream>>>(Pp, g2, be2, params, 32, 48);
  k_prep     <<<dim3(512), dim3(256), 0, stream>>>(xm, w1, b1, w2, b2, params, p);

  const bf16* dcur = p;
  for (int t = 0; t < 5; ++t){
    k_convstat<<<dim3(4096), dim3(256), 0, stream>>>(dcur, dw, P1);
    k_finloop <<<dim3(1),    dim3(256), 0, stream>>>(P1, P2, gd, bd, ww, gw, bw,
                                                     wh, gh, bh, params, t - 1, 1);
    k_bnwrite <<<dim3(4096), dim3(256), 0, stream>>>(dcur, dw, params, dbuf[t], P2);
    dcur = dbuf[t];
  }
  k_finloop<<<dim3(1), dim3(256), 0, stream>>>(P1, P2, gd, bd, ww, gw, bw,
                                               wh, gh, bh, params, 4, 0);
  k_final<<<dim3(2048), dim3(256), 0, stream>>>(p, dbuf[0], dbuf[1], dbuf[2],
                                                dbuf[3], dbuf[4], params, out);
}

// Round 6
// 271.396 us; speedup vs baseline: 2.9964x; 1.0220x over previous
//
#include <hip/hip_runtime.h>
#include <hip/hip_bf16.h>
#include <stdint.h>
#include <stddef.h>

#define HW 262144          // 512*512
#define EPSF 1e-5f

typedef __hip_bfloat16 bf16;

__device__ __forceinline__ float us2f(uint32_t u){
  union { uint32_t i; float f; } c; c.i = u << 16; return c.f;
}
__device__ __forceinline__ ushort f2bu(float v){
  union { bf16 h; ushort u; } c; c.h = __float2bfloat16(v); return c.u;
}
__device__ __forceinline__ float lrelu(float v){ return v > 0.0f ? v : 0.01f * v; }
__device__ __forceinline__ uint32_t umax2(uint32_t a, uint32_t b){ return a > b ? a : b; }

// ---------------------------------------------------------------------------
// K0a: quantize x to level k = rint(x*255/16), materialize reflect-padded u8
// plane [6][522 rows][pitch 528]
// ---------------------------------------------------------------------------
__global__ __launch_bounds__(256) void k_quant_pad(const float* __restrict__ x,
                                                   uint8_t* __restrict__ qpad){
  int idx = blockIdx.x * 256 + threadIdx.x;
  if (idx >= 6 * 522 * 522) return;
  int pw = idx % 522; int t = idx / 522; int ph = t % 522; int img = t / 522;
  int h = ph - 5; h = h < 0 ? -h : h; if (h > 511) h = 1022 - h;
  int w = pw - 5; w = w < 0 ? -w : w; if (w > 511) w = 1022 - w;
  float v = x[img * HW + h * 512 + w];
  int k = (int)rintf((v * 255.0f) / 16.0f);   // round-half-even, matches jnp.round
  qpad[img * (522 * 528) + ph * 528 + pw] = (uint8_t)k;
}

// ---------------------------------------------------------------------------
// K0b: 11x11 mode filter (LDS tile, rolled loops to avoid VGPR spill — r4/r5).
// ---------------------------------------------------------------------------
__global__ __launch_bounds__(256) void k_mode(const uint8_t* __restrict__ qpad,
                                              uint8_t* __restrict__ xm){
  __shared__ uint8_t tile[14 * 528];          // 7392 B
  int tid = threadIdx.x;
  int img = blockIdx.x >> 7;
  int h0  = (blockIdx.x & 127) << 2;          // first output row of block
  {
    const uint4* g4 = (const uint4*)(qpad + img * (522 * 528) + h0 * 528);
    uint4* t4 = (uint4*)tile;
    t4[tid] = g4[tid];                        // 0..255
    if (tid < 206) t4[tid + 256] = g4[tid + 256];   // 256..461 (462 total)
  }
  __syncthreads();
  int r4 = tid >> 6;                          // row within block 0..3
  int w0 = (tid & 63) << 3;                   // 0..504
  const uint8_t* base = tile + r4 * 528 + w0;
  uint32_t c0 = 0, c1 = 0, c2 = 0, c3 = 0, c4 = 0;
#define HINC(q) { uint32_t inc_ = 1u << (((q) & 3u) << 3); uint32_t rr_ = (q) >> 2; \
    c0 += (rr_==0u)?inc_:0u; c1 += (rr_==1u)?inc_:0u; c2 += (rr_==2u)?inc_:0u; \
    c3 += (rr_==3u)?inc_:0u; c4 += (rr_==4u)?inc_:0u; }
#define HDEC(q) { uint32_t inc_ = 1u << (((q) & 3u) << 3); uint32_t rr_ = (q) >> 2; \
    c0 -= (rr_==0u)?inc_:0u; c1 -= (rr_==1u)?inc_:0u; c2 -= (rr_==2u)?inc_:0u; \
    c3 -= (rr_==3u)?inc_:0u; c4 -= (rr_==4u)?inc_:0u; }
  #pragma unroll 1
  for (int r = 0; r < 11; ++r){
    const uint8_t* row = base + r * 528;
    #pragma unroll
    for (int j = 0; j < 11; ++j){ uint32_t q = row[j]; HINC(q); }
  }
  uint64_t packed = 0;
  #pragma unroll 1
  for (int s = 0; s < 8; ++s){
    // key(l) = (cnt<<5) | (16-l); max key -> max cnt, tie -> smallest level
#define KEY(reg, sh, l) (((((reg) >> (sh)) & 0xffu) << 5) | (16u - (uint32_t)(l)))
    uint32_t m0 = umax2(umax2(KEY(c0,0,0),  KEY(c0,8,1)),  umax2(KEY(c0,16,2),  KEY(c0,24,3)));
    uint32_t m1 = umax2(umax2(KEY(c1,0,4),  KEY(c1,8,5)),  umax2(KEY(c1,16,6),  KEY(c1,24,7)));
    uint32_t m2 = umax2(umax2(KEY(c2,0,8),  KEY(c2,8,9)),  umax2(KEY(c2,16,10), KEY(c2,24,11)));
    uint32_t m3 = umax2(umax2(KEY(c3,0,12), KEY(c3,8,13)), umax2(KEY(c3,16,14), KEY(c3,24,15)));
    uint32_t m  = umax2(umax2(umax2(m0, m1), umax2(m2, m3)), KEY(c4,0,16));
#undef KEY
    uint32_t lvl = 16u - (m & 31u);
    packed |= ((uint64_t)lvl) << (8 * s);
    if (s < 7){
      #pragma unroll
      for (int r = 0; r < 11; ++r){
        uint32_t qo = base[r * 528 + s];      HDEC(qo);
        uint32_t qn = base[r * 528 + s + 11]; HINC(qn);
      }
    }
  }
#undef HINC
#undef HDEC
  *(uint64_t*)(xm + img * HW + (h0 + r4) * 512 + w0) = packed;
}

// ---------------------------------------------------------------------------
// block reduction of per-thread su[16]/sq[16] -> partials[block][32]
// ---------------------------------------------------------------------------
__device__ __forceinline__ void reduce16(float* su, float* sq, float* __restrict__ partials){
  __shared__ float lsum[32];
  int tid = threadIdx.x;
  if (tid < 32) lsum[tid] = 0.0f;
  __syncthreads();
  #pragma unroll
  for (int o = 0; o < 16; ++o){
    float s = su[o], q = sq[o];
    #pragma unroll
    for (int off = 32; off >= 1; off >>= 1){
      s += __shfl_xor(s, off);
      q += __shfl_xor(q, off);
    }
    if ((tid & 63) == 0){ atomicAdd(&lsum[o], s); atomicAdd(&lsum[16 + o], q); }
  }
  __syncthreads();
  if (tid < 32) partials[blockIdx.x * 32 + tid] = lsum[tid];
}

// ---------------------------------------------------------------------------
// K1: stats of p1 = conv1x1(xm). 4 px/thread. grid 512 x 256.
// ---------------------------------------------------------------------------
__global__ __launch_bounds__(256) void k_stats1(const uint8_t* __restrict__ xm,
                                                const float* __restrict__ w1,
                                                const float* __restrict__ b1,
                                                float* __restrict__ partials){
  int t0 = (blockIdx.x * 256 + threadIdx.x) << 2;
  int b = t0 >> 18, hw = t0 & (HW - 1);
  uint32_t q0 = *(const uint32_t*)(xm + (b * 3 + 0) * HW + hw);
  uint32_t q1 = *(const uint32_t*)(xm + (b * 3 + 1) * HW + hw);
  uint32_t q2 = *(const uint32_t*)(xm + (b * 3 + 2) * HW + hw);
  float su[16], sq[16];
  #pragma unroll
  for (int o = 0; o < 16; ++o){ su[o] = 0.0f; sq[o] = 0.0f; }
  #pragma unroll
  for (int px = 0; px < 4; ++px){
    float x0 = (float)((q0 >> (8 * px)) & 0xffu) * 0.0625f;
    float x1 = (float)((q1 >> (8 * px)) & 0xffu) * 0.0625f;
    float x2 = (float)((q2 >> (8 * px)) & 0xffu) * 0.0625f;
    #pragma unroll
    for (int o = 0; o < 16; ++o){
      float v = b1[o] + w1[o*3]*x0 + w1[o*3+1]*x1 + w1[o*3+2]*x2;
      su[o] += v; sq[o] += v * v;
    }
  }
  reduce16(su, sq, partials);
}

// ---------------------------------------------------------------------------
// K2: recompute p1, bn1+lrelu, p2 = conv1x1, stats of p2. 4 px/thread.
// ---------------------------------------------------------------------------
__global__ __launch_bounds__(256) void k_stats2(const uint8_t* __restrict__ xm,
                                                const float* __restrict__ w1,
                                                const float* __restrict__ b1,
                                                const float* __restrict__ w2,
                                                const float* __restrict__ b2,
                                                const float* __restrict__ params,
                                                float* __restrict__ partials){
  int t0 = (blockIdx.x * 256 + threadIdx.x) << 2;
  int b = t0 >> 18, hw = t0 & (HW - 1);
  uint32_t q0 = *(const uint32_t*)(xm + (b * 3 + 0) * HW + hw);
  uint32_t q1 = *(const uint32_t*)(xm + (b * 3 + 1) * HW + hw);
  uint32_t q2 = *(const uint32_t*)(xm + (b * 3 + 2) * HW + hw);
  float tv[4][16];
  #pragma unroll
  for (int px = 0; px < 4; ++px){
    float x0 = (float)((q0 >> (8 * px)) & 0xffu) * 0.0625f;
    float x1 = (float)((q1 >> (8 * px)) & 0xffu) * 0.0625f;
    float x2 = (float)((q2 >> (8 * px)) & 0xffu) * 0.0625f;
    #pragma unroll
    for (int o = 0; o < 16; ++o){
      float v = b1[o] + w1[o*3]*x0 + w1[o*3+1]*x1 + w1[o*3+2]*x2;
      tv[px][o] = lrelu(v * params[o] + params[16 + o]);
    }
  }
  float su[16], sq[16];
  #pragma unroll
  for (int o = 0; o < 16; ++o){ su[o] = 0.0f; sq[o] = 0.0f; }
  #pragma unroll
  for (int o = 0; o < 16; ++o){
    #pragma unroll
    for (int px = 0; px < 4; ++px){
      float acc = b2[o];
      #pragma unroll
      for (int c = 0; c < 16; ++c) acc = fmaf(w2[o*16 + c], tv[px][c], acc);
      su[o] += acc; sq[o] += acc * acc;
    }
  }
  reduce16(su, sq, partials);
}

// ---------------------------------------------------------------------------
// K3: recompute p2, bn2+lrelu, write p (bf16). 4 px/thread.
// ---------------------------------------------------------------------------
__global__ __launch_bounds__(256) void k_prep(const uint8_t* __restrict__ xm,
                                              const float* __restrict__ w1,
                                              const float* __restrict__ b1,
                                              const float* __restrict__ w2,
                                              const float* __restrict__ b2,
                                              const float* __restrict__ params,
                                              bf16* __restrict__ p){
  int t0 = (blockIdx.x * 256 + threadIdx.x) << 2;
  int b = t0 >> 18, hw = t0 & (HW - 1);
  uint32_t q0 = *(const uint32_t*)(xm + (b * 3 + 0) * HW + hw);
  uint32_t q1 = *(const uint32_t*)(xm + (b * 3 + 1) * HW + hw);
  uint32_t q2 = *(const uint32_t*)(xm + (b * 3 + 2) * HW + hw);
  float tv[4][16];
  #pragma unroll
  for (int px = 0; px < 4; ++px){
    float x0 = (float)((q0 >> (8 * px)) & 0xffu) * 0.0625f;
    float x1 = (float)((q1 >> (8 * px)) & 0xffu) * 0.0625f;
    float x2 = (float)((q2 >> (8 * px)) & 0xffu) * 0.0625f;
    #pragma unroll
    for (int o = 0; o < 16; ++o){
      float v = b1[o] + w1[o*3]*x0 + w1[o*3+1]*x1 + w1[o*3+2]*x2;
      tv[px][o] = lrelu(v * params[o] + params[16 + o]);
    }
  }
  #pragma unroll
  for (int o = 0; o < 16; ++o){
    uint32_t w01 = 0, w23 = 0;
    #pragma unroll
    for (int px = 0; px < 4; ++px){
      float acc = b2[o];
      #pragma unroll
      for (int c = 0; c < 16; ++c) acc = fmaf(w2[o*16 + c], tv[px][c], acc);
      float v = lrelu(acc * params[32 + o] + params[48 + o]);
      uint32_t bits = (uint32_t)f2bu(v);
      if (px == 0) w01 = bits;
      else if (px == 1) w01 |= bits << 16;
      else if (px == 2) w23 = bits;
      else w23 |= bits << 16;
    }
    uint2 ov; ov.x = w01; ov.y = w23;
    *(uint2*)((ushort*)p + (b * 16 + o) * HW + hw) = ov;
  }
}

// ---------------------------------------------------------------------------
// row loader for depthwise conv: 10 values (cols w0-1 .. w0+8), zero-padded.
// Works on global or LDS ushort rows (stride-512, 16B-aligned at w0).
// ---------------------------------------------------------------------------
__device__ __forceinline__ void load_row10(const ushort* __restrict__ rp, int w0, float* v){
  uint4 cc = *(const uint4*)(rp + w0);
  uint32_t l = (w0 == 0)   ? 0u : (uint32_t)rp[w0 - 1];
  uint32_t r = (w0 == 504) ? 0u : (uint32_t)rp[w0 + 8];
  v[0] = us2f(l);
  v[1] = us2f(cc.x & 0xffffu); v[2] = us2f(cc.x >> 16);
  v[3] = us2f(cc.y & 0xffffu); v[4] = us2f(cc.y >> 16);
  v[5] = us2f(cc.z & 0xffffu); v[6] = us2f(cc.z >> 16);
  v[7] = us2f(cc.w & 0xffffu); v[8] = us2f(cc.w >> 16);
  v[9] = us2f(r);
}

__device__ __forceinline__ void zero_row10(float* v){
  #pragma unroll
  for (int j = 0; j < 10; ++j) v[j] = 0.0f;
}

__device__ __forceinline__ void reduce2(float s, float q, float* __restrict__ partials){
  __shared__ float l2[2];
  int tid = threadIdx.x;
  if (tid < 2) l2[tid] = 0.0f;
  __syncthreads();
  #pragma unroll
  for (int off = 32; off >= 1; off >>= 1){
    s += __shfl_xor(s, off);
    q += __shfl_xor(q, off);
  }
  if ((tid & 63) == 0){ atomicAdd(&l2[0], s); atomicAdd(&l2[1], q); }
  __syncthreads();
  if (tid < 2) partials[blockIdx.x * 2 + tid] = l2[tid];
}

// ---------------------------------------------------------------------------
// A: conv stats of p only (first loop iteration input). grid 4096.
// ---------------------------------------------------------------------------
__global__ __launch_bounds__(256) void k_convstat(const bf16* __restrict__ d,
                                                  const float* __restrict__ dw,
                                                  float* __restrict__ P1){
  int bid = blockIdx.x;
  int plane = bid >> 7, rg = bid & 127;
  int f = plane & 15;
  int tid = threadIdx.x;
  int h  = (rg << 2) + (tid >> 6);
  int w0 = (tid & 63) << 3;
  const ushort* pl = (const ushort*)d + plane * HW;
  float wf[9];
  #pragma unroll
  for (int i = 0; i < 9; ++i) wf[i] = dw[f * 9 + i];
  float v[3][10];
  #pragma unroll
  for (int dy = 0; dy < 3; ++dy){
    int row = h + dy - 1;
    if ((unsigned)row < 512u) load_row10(pl + row * 512, w0, v[dy]);
    else zero_row10(v[dy]);
  }
  float s = 0.0f, q = 0.0f;
  #pragma unroll
  for (int k = 0; k < 8; ++k){
    float acc = 0.0f;
    #pragma unroll
    for (int dy = 0; dy < 3; ++dy)
      #pragma unroll
      for (int dx = 0; dx < 3; ++dx)
        acc = fmaf(wf[dy*3 + dx], v[dy][k + dx], acc);
    s += acc; q += acc * acc;
  }
  reduce2(s, q, P1);
}

// ---------------------------------------------------------------------------
// channel-f reduction of a [32 planes][128 rg][2] partials buffer via a
// 256-entry double LDS tree. All blocks compute bit-identical sums.
// ---------------------------------------------------------------------------
__device__ __forceinline__ void chan_reduce(const float* __restrict__ P, int f, int tid,
                                            double* rS, double* rQ,
                                            double& S, double& Q){
  int blk = (((tid >> 7) * 16 + f) << 7) + (tid & 127);   // b = tid>>7, rg = tid&127
  rS[tid] = (double)P[blk * 2];
  rQ[tid] = (double)P[blk * 2 + 1];
  __syncthreads();
  for (int st = 128; st >= 1; st >>= 1){
    if (tid < st){ rS[tid] += rS[tid + st]; rQ[tid] += rQ[tid + st]; }
    __syncthreads();
  }
  S = rS[0]; Q = rQ[0];
  __syncthreads();
}

// ---------------------------------------------------------------------------
// FUSED loop kernel. grid 4096 (plane x 4-row group), 256 threads.
//   prologue: bnA params (sc,sh) for channel f from P1in (double tree)
//   main:     conv(din)+bn+lrelu -> dout (global) + LDS strip; P2 stats of d
//   halo:     recompute rows h0-1 / h0+4 of d into LDS (bit-identical to the
//             neighboring blocks' stored values: same math, same rounding)
//   epilogue: conv(d) stats from LDS strip -> P1out (next iteration's stats)
// ---------------------------------------------------------------------------
__global__ __launch_bounds__(256) void k_bnfused(const bf16* __restrict__ din,
                                                 const float* __restrict__ dw,
                                                 const float* __restrict__ gd,
                                                 const float* __restrict__ bd,
                                                 const float* __restrict__ P1in,
                                                 bf16* __restrict__ dout,
                                                 float* __restrict__ P2out,
                                                 float* __restrict__ P1out){
  __shared__ double rS[256], rQ[256];
  __shared__ ushort strip[6][512];
  __shared__ float acc4[4];
  int bid = blockIdx.x;
  int plane = bid >> 7, rg = bid & 127;
  int f = plane & 15;
  int tid = threadIdx.x;

  double S, Q;
  chan_reduce(P1in, f, tid, rS, rQ, S, Q);
  float sc, sh;
  {
    double m = S / 524288.0;
    double v = Q / 524288.0 - m * m;
    sc = gd[f] / sqrtf((float)v + EPSF);
    sh = bd[f] - (float)m * sc;
  }
  if (tid < 4) acc4[tid] = 0.0f;
  __syncthreads();

  int h0 = rg << 2;
  int h  = h0 + (tid >> 6);
  int w0 = (tid & 63) << 3;
  const ushort* pl = (const ushort*)din + plane * HW;
  float wf[9];
  #pragma unroll
  for (int i = 0; i < 9; ++i) wf[i] = dw[f * 9 + i];

  // main rows
  float s2 = 0.0f, q2 = 0.0f;
  {
    float v[3][10];
    #pragma unroll
    for (int dy = 0; dy < 3; ++dy){
      int row = h + dy - 1;
      if ((unsigned)row < 512u) load_row10(pl + row * 512, w0, v[dy]);
      else zero_row10(v[dy]);
    }
    uint32_t ob[4];
    #pragma unroll
    for (int k = 0; k < 8; ++k){
      float acc = 0.0f;
      #pragma unroll
      for (int dy = 0; dy < 3; ++dy)
        #pragma unroll
        for (int dx = 0; dx < 3; ++dx)
          acc = fmaf(wf[dy*3 + dx], v[dy][k + dx], acc);
      float vv = lrelu(acc * sc + sh);
      uint32_t bits = (uint32_t)f2bu(vv);
      if ((k & 1) == 0) ob[k >> 1] = bits; else ob[k >> 1] |= bits << 16;
      s2 += vv; q2 += vv * vv;
    }
    uint4 ov; ov.x = ob[0]; ov.y = ob[1]; ov.z = ob[2]; ov.w = ob[3];
    *(uint4*)((ushort*)dout + plane * HW + h * 512 + w0) = ov;
    *(uint4*)&strip[1 + (tid >> 6)][w0] = ov;
  }

  // halo rows (threads 0..63 -> row h0-1, 64..127 -> row h0+4)
  if (tid < 128){
    int hh = (tid < 64) ? (h0 - 1) : (h0 + 4);
    int si = (tid < 64) ? 0 : 5;
    int wh0 = (tid & 63) << 3;
    uint4 hv; hv.x = 0; hv.y = 0; hv.z = 0; hv.w = 0;
    if ((unsigned)hh < 512u){
      float v[3][10];
      #pragma unroll
      for (int dy = 0; dy < 3; ++dy){
        int row = hh + dy - 1;
        if ((unsigned)row < 512u) load_row10(pl + row * 512, wh0, v[dy]);
        else zero_row10(v[dy]);
      }
      uint32_t hb[4];
      #pragma unroll
      for (int k = 0; k < 8; ++k){
        float acc = 0.0f;
        #pragma unroll
        for (int dy = 0; dy < 3; ++dy)
          #pragma unroll
          for (int dx = 0; dx < 3; ++dx)
            acc = fmaf(wf[dy*3 + dx], v[dy][k + dx], acc);
        float vv = lrelu(acc * sc + sh);
        uint32_t bits = (uint32_t)f2bu(vv);
        if ((k & 1) == 0) hb[k >> 1] = bits; else hb[k >> 1] |= bits << 16;
      }
      hv.x = hb[0]; hv.y = hb[1]; hv.z = hb[2]; hv.w = hb[3];
    }
    *(uint4*)&strip[si][wh0] = hv;
  }
  __syncthreads();

  // conv stats over the staged d strip
  float s1 = 0.0f, q1 = 0.0f;
  {
    int si = 1 + (tid >> 6);
    float v[3][10];
    #pragma unroll
    for (int dy = 0; dy < 3; ++dy)
      load_row10(&strip[si - 1 + dy][0], w0, v[dy]);
    #pragma unroll
    for (int k = 0; k < 8; ++k){
      float acc = 0.0f;
      #pragma unroll
      for (int dy = 0; dy < 3; ++dy)
        #pragma unroll
        for (int dx = 0; dx < 3; ++dx)
          acc = fmaf(wf[dy*3 + dx], v[dy][k + dx], acc);
      s1 += acc; q1 += acc * acc;
    }
  }

  // epilogue: reduce (s2,q2,s1,q1) across block, write partials
  #pragma unroll
  for (int off = 32; off >= 1; off >>= 1){
    s2 += __shfl_xor(s2, off);
    q2 += __shfl_xor(q2, off);
    s1 += __shfl_xor(s1, off);
    q1 += __shfl_xor(q1, off);
  }
  if ((tid & 63) == 0){
    atomicAdd(&acc4[0], s2); atomicAdd(&acc4[1], q2);
    atomicAdd(&acc4[2], s1); atomicAdd(&acc4[3], q1);
  }
  __syncthreads();
  if (tid < 2)      P2out[bid * 2 + tid]       = acc4[tid];
  else if (tid < 4) P1out[bid * 2 + (tid - 2)] = acc4[tid];
}

// ---------------------------------------------------------------------------
// finalize: prepare-stage BN (512-block x 32 partials layout)
// ---------------------------------------------------------------------------
__global__ __launch_bounds__(256) void k_fin_prep(const float* __restrict__ partials,
                                                  const float* __restrict__ g,
                                                  const float* __restrict__ bb,
                                                  float* __restrict__ params,
                                                  int offS, int offT){
  int tid = threadIdx.x;
  int o = tid & 15, c = tid >> 4;
  double S = 0.0, Q = 0.0;
  for (int i = c * 32; i < (c + 1) * 32; ++i){
    S += (double)partials[i * 32 + o];
    Q += (double)partials[i * 32 + 16 + o];
  }
  __shared__ double lS[256], lQ[256];
  lS[tid] = S; lQ[tid] = Q; __syncthreads();
  for (int st = 8; st >= 1; st >>= 1){
    if (c < st){ lS[tid] += lS[tid + st * 16]; lQ[tid] += lQ[tid + st * 16]; }
    __syncthreads();
  }
  if (tid < 16){
    double m = lS[tid] / 524288.0;
    double v = lQ[tid] / 524288.0 - m * m;
    float sc = g[tid] / sqrtf((float)v + EPSF);
    params[offS + tid] = sc;
    params[offT + tid] = bb[tid] - (float)m * sc;
  }
}

// ---------------------------------------------------------------------------
// F: assemble out. Prologue computes the 5 wdt/hgt param quadruples for this
// block's f from P2 (double tree, bit-identical across blocks). 8 px/thread.
// ---------------------------------------------------------------------------
__device__ __forceinline__ void load8(const ushort* __restrict__ ptr, float* v){
  uint4 cc = *(const uint4*)ptr;
  v[0] = us2f(cc.x & 0xffffu); v[1] = us2f(cc.x >> 16);
  v[2] = us2f(cc.y & 0xffffu); v[3] = us2f(cc.y >> 16);
  v[4] = us2f(cc.z & 0xffffu); v[5] = us2f(cc.z >> 16);
  v[6] = us2f(cc.w & 0xffffu); v[7] = us2f(cc.w >> 16);
}

__global__ __launch_bounds__(256) void k_final(const bf16* __restrict__ p,
                                               const bf16* __restrict__ d1,
                                               const bf16* __restrict__ d2,
                                               const bf16* __restrict__ d3,
                                               const bf16* __restrict__ d4,
                                               const bf16* __restrict__ d5,
                                               const float* __restrict__ P2,
                                               const float* __restrict__ ww,
                                               const float* __restrict__ gw,
                                               const float* __restrict__ bw,
                                               const float* __restrict__ wh,
                                               const float* __restrict__ gh,
                                               const float* __restrict__ bh,
                                               float* __restrict__ out){
  __shared__ double rS[256], rQ[256];
  int tid = threadIdx.x;
  int f = blockIdx.x >> 7;                      // 128 blocks per f
  float swA[5], twA[5], shA[5], thA[5];
  #pragma unroll
  for (int t = 0; t < 5; ++t){
    double S, Q;
    chan_reduce(P2 + t * 8192, f, tid, rS, rQ, S, Q);
    float m = (float)(S / 524288.0);
    float v = (float)(Q / 524288.0) - m * m;
    swA[t] = ww[f] * gw[f] / sqrtf(ww[f] * ww[f] * v + EPSF);
    twA[t] = bw[f] - m * swA[t];
    shA[t] = wh[f] * gh[f] / sqrtf(wh[f] * wh[f] * v + EPSF);
    thA[t] = bh[f] - m * shA[t];
  }

  int gid = blockIdx.x * 256 + tid;             // 0 .. 524287
  int hw = (gid & 32767) << 3;
  int fo = f * HW + hw;
  int f1 = (16 + f) * HW + hw;
  float pf[8], pg[8];
  load8((const ushort*)p + fo, pf);
  load8((const ushort*)p + f1, pg);
  float a00[8], a01[8], a10[8], a11[8];
  #pragma unroll
  for (int k = 0; k < 8; ++k){ a00[k] = pf[k]; a01[k] = pg[k]; a10[k] = pf[k]; a11[k] = pg[k]; }
  const bf16* dptrs[5] = {d1, d2, d3, d4, d5};
  #pragma unroll
  for (int t = 0; t < 5; ++t){
    const ushort* dp = (const ushort*)dptrs[t];
    float dv0[8], dv1[8];
    load8(dp + fo, dv0);
    load8(dp + f1, dv1);
    float sw = swA[t], tw = twA[t], sh = shA[t], th = thA[t];
    #pragma unroll
    for (int k = 0; k < 8; ++k){
      a00[k] += lrelu(fmaf(dv0[k], sw, tw));
      a01[k] += lrelu(fmaf(dv0[k], sh, th));
      a10[k] += lrelu(fmaf(dv1[k], sw, tw));
      a11[k] += lrelu(fmaf(dv1[k], sh, th));
    }
  }
  #pragma unroll
  for (int half = 0; half < 2; ++half){
    float4 v0 = { a00[half*4+0], a00[half*4+1], a00[half*4+2], a00[half*4+3] };
    float4 v1 = { a01[half*4+0], a01[half*4+1], a01[half*4+2], a01[half*4+3] };
    float4 v2 = { a10[half*4+0], a10[half*4+1], a10[half*4+2], a10[half*4+3] };
    float4 v3 = { a11[half*4+0], a11[half*4+1], a11[half*4+2], a11[half*4+3] };
    *(float4*)(out + f * HW + hw + half*4)        = v0;
    *(float4*)(out + (16 + f) * HW + hw + half*4) = v1;
    *(float4*)(out + (32 + f) * HW + hw + half*4) = v2;
    *(float4*)(out + (48 + f) * HW + hw + half*4) = v3;
  }
}

// ---------------------------------------------------------------------------
extern "C" void kernel_launch(void* const* d_in, const int* in_sizes, int n_in,
                              void* d_out, int out_size, void* d_ws, size_t ws_size,
                              hipStream_t stream){
  (void)in_sizes; (void)n_in; (void)out_size;
  const float* x   = (const float*)d_in[0];
  const float* w1  = (const float*)d_in[1];
  const float* b1  = (const float*)d_in[2];
  const float* g1  = (const float*)d_in[3];
  const float* be1 = (const float*)d_in[4];
  const float* w2  = (const float*)d_in[5];
  const float* b2  = (const float*)d_in[6];
  const float* g2  = (const float*)d_in[7];
  const float* be2 = (const float*)d_in[8];
  const float* dw  = (const float*)d_in[9];
  const float* gd  = (const float*)d_in[10];
  const float* bd  = (const float*)d_in[11];
  const float* ww  = (const float*)d_in[12];
  const float* gw  = (const float*)d_in[13];
  const float* bw  = (const float*)d_in[14];
  const float* wh  = (const float*)d_in[15];
  const float* gh  = (const float*)d_in[16];
  const float* bh  = (const float*)d_in[17];
  float* out = (float*)d_out;

  char* ws = (char*)d_ws;
  size_t off = 0;
  auto alloc = [&](size_t sz) -> void* {
    void* ptr = ws + off;
    off = (off + sz + 4095) & ~(size_t)4095;
    return ptr;
  };
  uint8_t* qpad  = (uint8_t*)alloc((size_t)6 * 522 * 528);
  uint8_t* xm    = (uint8_t*)alloc((size_t)6 * HW);
  bf16*    p     = (bf16*)   alloc((size_t)32 * HW * 2);
  bf16*    dbuf[5];
  for (int i = 0; i < 5; ++i) dbuf[i] = (bf16*)alloc((size_t)32 * HW * 2);
  float*   Pp     = (float*)  alloc((size_t)512 * 32 * 4);
  float*   P1a    = (float*)  alloc((size_t)4096 * 2 * 4);
  float*   P1b    = (float*)  alloc((size_t)4096 * 2 * 4);
  float*   P2     = (float*)  alloc((size_t)5 * 4096 * 2 * 4);
  float*   params = (float*)  alloc(4096);
  if (ws_size < off) return;   // workspace too small: fail visibly (untouched out)

  k_quant_pad<<<dim3((6*522*522 + 255)/256), dim3(256), 0, stream>>>(x, qpad);
  k_mode     <<<dim3(768), dim3(256), 0, stream>>>(qpad, xm);
  k_stats1   <<<dim3(512), dim3(256), 0, stream>>>(xm, w1, b1, Pp);
  k_fin_prep <<<dim3(1),   dim3(256), 0, stream>>>(Pp, g1, be1, params, 0, 16);
  k_stats2   <<<dim3(512), dim3(256), 0, stream>>>(xm, w1, b1, w2, b2, params, Pp);
  k_fin_prep <<<dim3(1),   dim3(256), 0, stream>>>(Pp, g2, be2, params, 32, 48);
  k_prep     <<<dim3(512), dim3(256), 0, stream>>>(xm, w1, b1, w2, b2, params, p);
  k_convstat <<<dim3(4096), dim3(256), 0, stream>>>(p, dw, P1a);

  const bf16* dcur = p;
  float* Pin = P1a; float* Pout = P1b;
  for (int t = 0; t < 5; ++t){
    k_bnfused<<<dim3(4096), dim3(256), 0, stream>>>(dcur, dw, gd, bd, Pin,
                                                    dbuf[t], P2 + t * 8192, Pout);
    dcur = dbuf[t];
    float* tmp = Pin; Pin = Pout; Pout = tmp;
  }
  k_final<<<dim3(2048), dim3(256), 0, stream>>>(p, dbuf[0], dbuf[1], dbuf[2],
                                                dbuf[3], dbuf[4], P2,
                                                ww, gw, bw, wh, gh, bh, out);
}